// Round 5
// baseline (1724.912 us; speedup 1.0000x reference)
//
#include <hip/hip_runtime.h>
#include <hip/hip_fp16.h>
#include <cmath>

typedef unsigned short u16;
typedef unsigned int   u32;

// Problem constants
constexpr int B_ = 8, T_ = 32, N_ = 24, D_ = 128;
constexpr int BT_ = B_ * T_;            // 256
constexpr int VW_ = N_ * N_;            // 576
constexpr int BTN_ = BT_ * N_;          // 6144
constexpr int BTVW_ = BT_ * VW_;        // 147456
constexpr int P_ = 3;
constexpr int C_ = 6;

__device__ __forceinline__ float bits2f(u32 u) { float f; __builtin_memcpy(&f, &u, 4); return f; }
__device__ __forceinline__ float bf2f(u16 h) { return bits2f(((u32)h) << 16); }
__device__ __forceinline__ u16 f2bf(float f) {
    u32 u; __builtin_memcpy(&u, &f, 4);
    u32 r = u + 0x7FFFu + ((u >> 16) & 1u);
    return (u16)(r >> 16);
}
__device__ __forceinline__ float h2f(u16 b) {
    __half h; __builtin_memcpy(&h, &b, 2);
    return __half2float(h);
}
__device__ __forceinline__ float sigm(float x) { return 1.0f / (1.0f + expf(-x)); }

// flag: 0 = bf16, 1 = fp32, 2 = fp16
__device__ __forceinline__ float ldany(const void* p, size_t i, int flg) {
    if (flg == 1) return ((const float*)p)[i];
    if (flg == 0) return bf2f(((const u16*)p)[i]);
    return h2f(((const u16*)p)[i]);
}

// ---------------------------------------------------------------------------
// Dtype detection: node_resnet [bt,d,n] has zeros exactly at n >= nnr[bt].
// ---------------------------------------------------------------------------
__global__ __launch_bounds__(256) void k_detect(const void* __restrict__ node,
                                                const int* __restrict__ nnr,
                                                int* __restrict__ flag) {
    __shared__ int sc[3];
    const int tid = threadIdx.x;
    if (tid < 3) sc[tid] = 0;
    __syncthreads();
    int loc0 = 0, loc1 = 0, loc2 = 0;
    for (int c = tid; c < 768; c += 256) {
        const int bt = c / 96, rem = c % 96;
        const int d = rem / 24, n = rem % 24;
        const bool ez = (n >= nnr[bt]);
        const size_t i = (size_t)bt * 3072 + d * 24 + n;
        {
            const float v = bf2f(((const u16*)node)[i]);
            loc0 += (ez ? (v == 0.0f) : (v != 0.0f && fabsf(v) < 100.0f)) ? 1 : 0;
        }
        {
            const float v = ((const float*)node)[i];
            loc1 += (isfinite(v) && (ez ? (v == 0.0f) : (v != 0.0f && fabsf(v) < 100.0f))) ? 1 : 0;
        }
        {
            const float v = h2f(((const u16*)node)[i]);
            loc2 += (isfinite(v) && (ez ? (v == 0.0f) : (v != 0.0f && fabsf(v) < 100.0f))) ? 1 : 0;
        }
    }
    atomicAdd(&sc[0], loc0);
    atomicAdd(&sc[1], loc1);
    atomicAdd(&sc[2], loc2);
    __syncthreads();
    if (tid == 0) {
        int f = 0, best = sc[0];
        if (sc[1] > best) { f = 1; best = sc[1]; }
        if (sc[2] > best) { f = 2; }
        flag[0] = f;
    }
}

// ---------------------------------------------------------------------------
// Canonicalize ALL weight/bias arrays to bf16 in one launch.
// ---------------------------------------------------------------------------
struct CvtArgs {
    const void* src[17];
    u16* dst[17];
    int start[18];   // cumulative element offsets; start[17] = total
};

__global__ __launch_bounds__(256) void k_convall(CvtArgs a, const int* __restrict__ flag) {
    const int idx = blockIdx.x * 256 + threadIdx.x;
    if (idx >= a.start[17]) return;
    int s = 0;
#pragma unroll
    for (int i = 1; i < 17; ++i) s += (idx >= a.start[i]) ? 1 : 0;
    const int off = idx - a.start[s];
    const int flg = flag[0];
    u16 v;
    if (flg == 0) v = ((const u16*)a.src[s])[off];
    else if (flg == 1) v = f2bf(((const float*)a.src[s])[off]);
    else v = f2bf(h2f(((const u16*)a.src[s])[off]));
    a.dst[s][off] = v;
}

// Shared register-tile GEMM over K=128. R rows per row-group.
// xs rows (stride 128 fp32); Wc swizzled bf16:
// Wc[dc*512 + oj*128 + og*4 + dj] = W[(og*4+oj)*128 + dc*4 + dj].
template <int R>
__device__ __forceinline__ void tile_gemm(const float* xs, const u16* Wc,
                                          int og, int rg, float acc[R][4]) {
#pragma unroll
    for (int r = 0; r < R; ++r)
#pragma unroll
        for (int oj = 0; oj < 4; ++oj) acc[r][oj] = 0.0f;
    for (int dc = 0; dc < 32; ++dc) {
        float4 xv[R];
#pragma unroll
        for (int r = 0; r < R; ++r) xv[r] = *(const float4*)&xs[(rg * R + r) * 128 + dc * 4];
#pragma unroll
        for (int oj = 0; oj < 4; ++oj) {
            const uint2 wu = *(const uint2*)&Wc[dc * 512 + oj * 128 + og * 4];
            const float w0 = bits2f(wu.x << 16), w1 = bits2f(wu.x & 0xFFFF0000u);
            const float w2f = bits2f(wu.y << 16), w3 = bits2f(wu.y & 0xFFFF0000u);
#pragma unroll
            for (int r = 0; r < R; ++r)
                acc[r][oj] = fmaf(xv[r].w, w3,
                             fmaf(xv[r].z, w2f,
                             fmaf(xv[r].y, w1,
                             fmaf(xv[r].x, w0, acc[r][oj]))));
        }
    }
}

// ---------------------------------------------------------------------------
// Transpose node_resnet [bt, d, n] -> HN [bt, n, d] fp32. grid = BT_
// ---------------------------------------------------------------------------
__global__ __launch_bounds__(256) void k_transpose_node(const void* __restrict__ node,
                                                        float* __restrict__ HN,
                                                        const int* __restrict__ flag) {
    const int bt = blockIdx.x;
    const int flg = flag[0];
    for (int f = threadIdx.x; f < 3072; f += 256) {
        const int d = f / 24, n = f - d * 24;
        HN[(size_t)bt * 3072 + n * 128 + d] = ldany(node, (size_t)bt * 3072 + f, flg);
    }
}

// ---------------------------------------------------------------------------
// LSTM Whh transpose: WT[kk*1024 + j*2 + p] = Whh[j*128 + kk*2 + p]  (bf16)
// ---------------------------------------------------------------------------
__global__ __launch_bounds__(256) void k_wtprep(const u16* __restrict__ Whh,
                                                u16* __restrict__ WThh) {
    const int idx = blockIdx.x * 256 + threadIdx.x;
    const int kk = idx >> 10;
    const int rem = idx & 1023;
    const int j = rem >> 1, p = rem & 1;
    WThh[idx] = Whh[j * 128 + kk * 2 + p];
}

// ---------------------------------------------------------------------------
// XW = msg_Wh @ h_node. 192 blocks x 32 rows, 256 threads (4x4 tiles).
// ---------------------------------------------------------------------------
__global__ __launch_bounds__(256) void k_xw(const float* __restrict__ HN, const u16* __restrict__ W,
                                            float* __restrict__ XW) {
    __shared__ __align__(16) u16 Wc[16384];
    __shared__ __align__(16) float xs[4096];
    const int tid = threadIdx.x;
    const int og = tid & 31, rg = tid >> 5;
    for (int f = tid; f < 16384; f += 256) {
        const int dj = f & 3, o_g = (f >> 2) & 31, oj = (f >> 7) & 3, dc = f >> 9;
        Wc[f] = W[((o_g * 4 + oj) << 7) + (dc << 2) + dj];
    }
    const int rowBase = blockIdx.x * 32;
    for (int f = tid; f < 4096; f += 256) xs[f] = HN[(size_t)rowBase * 128 + f];
    __syncthreads();
    float acc[4][4];
    tile_gemm<4>(xs, Wc, og, rg, acc);
#pragma unroll
    for (int r = 0; r < 4; ++r) {
        const int row = rowBase + rg * 4 + r;
        float4 o4;
        o4.x = acc[r][0]; o4.y = acc[r][1]; o4.z = acc[r][2]; o4.w = acc[r][3];
        *(float4*)&XW[(size_t)row * 128 + og * 4] = o4;
    }
}

// ---------------------------------------------------------------------------
// GI = h_node @ lstm_Wih^T + (bih + bhh). grid dim3(192, 4), 256 threads.
// Row order matches HN ((bb*T+t)*N+n); 512 cols (y picks 128-chunk).
// ---------------------------------------------------------------------------
__global__ __launch_bounds__(256) void k_gi(const float* __restrict__ HN, const u16* __restrict__ W,
                                            const u16* __restrict__ bih, const u16* __restrict__ bhh,
                                            float* __restrict__ GI) {
    __shared__ __align__(16) u16 Wc[16384];
    __shared__ __align__(16) float xs[4096];
    __shared__ float bias_s[128];
    const int tid = threadIdx.x;
    const int og = tid & 31, rg = tid >> 5;
    const u16* Wp = W + (size_t)blockIdx.y * 16384;
    const int ocol = blockIdx.y * 128;
    for (int f = tid; f < 16384; f += 256) {
        const int dj = f & 3, o_g = (f >> 2) & 31, oj = (f >> 7) & 3, dc = f >> 9;
        Wc[f] = Wp[((o_g * 4 + oj) << 7) + (dc << 2) + dj];
    }
    if (tid < 128) bias_s[tid] = bf2f(bih[ocol + tid]) + bf2f(bhh[ocol + tid]);
    const int rowBase = blockIdx.x * 32;
    for (int f = tid; f < 4096; f += 256) xs[f] = HN[(size_t)rowBase * 128 + f];
    __syncthreads();
    float acc[4][4];
    tile_gemm<4>(xs, Wc, og, rg, acc);
#pragma unroll
    for (int r = 0; r < 4; ++r) {
        const int row = rowBase + rg * 4 + r;
        float4 o4;
        o4.x = acc[r][0] + bias_s[og * 4 + 0];
        o4.y = acc[r][1] + bias_s[og * 4 + 1];
        o4.z = acc[r][2] + bias_s[og * 4 + 2];
        o4.w = acc[r][3] + bias_s[og * 4 + 3];
        *(float4*)&GI[(size_t)row * 512 + ocol + og * 4] = o4;
    }
}

// ---------------------------------------------------------------------------
// Unified per-(bt,v) edge kernel. 384 threads = 32 og-lanes x 12 row-groups
// (2 rows each).
//  DO_MSG: me = We @ e_vw (raw); gv = sigm(adj)*relu(xw_w + me + mb) for valid
//          pairs (else keep raw row -> h_edge); MV[v] = sum_w gv.
//  DO_ADJ: adj' = W2 . relu(W1 @ xs + b1) + b2 over current xs rows.
// ---------------------------------------------------------------------------
template <bool DO_MSG, bool DO_ADJ>
__global__ __launch_bounds__(384) void k_edge(
    const void* __restrict__ edge, const int* __restrict__ flag,
    const float* __restrict__ XW,
    const u16* __restrict__ We, const u16* __restrict__ msgb,
    const u16* __restrict__ W1, const u16* __restrict__ b1,
    const u16* __restrict__ W2, const u16* __restrict__ b2,
    const int* __restrict__ nnr, float* __restrict__ ADJ,
    float* __restrict__ MV) {
    __shared__ __align__(16) u16 Wc[16384];
    __shared__ __align__(16) float xs[24 * 128];
    __shared__ __align__(16) float xw_s[24 * 128];
    __shared__ float mb_s[128];
    __shared__ float b1_s[128];
    __shared__ float w2_s[128];
    __shared__ float gate_s[24];
    const int tid = threadIdx.x;
    const int og = tid & 31, rg = tid >> 5;   // rg 0..11
    const int blk = blockIdx.x;
    const int bt = blk / N_, v = blk - bt * N_;
    const int nv = nnr[bt];
    const int flg = flag[0];
    const size_t rowbase = (size_t)bt * VW_ + (size_t)v * N_;
    const size_t ebase = (size_t)bt * D_ * VW_ + (size_t)v * N_;

    // stage raw edge rows, d-major walk for coalescing: xs[w*128+d]
    if (flg == 1) {
        for (int f = tid; f < 3072; f += 384) {
            const int d = f / 24, w = f - d * 24;
            xs[w * 128 + d] = ((const float*)edge)[ebase + (size_t)d * VW_ + w];
        }
    } else if (flg == 0) {
        for (int f = tid; f < 3072; f += 384) {
            const int d = f / 24, w = f - d * 24;
            xs[w * 128 + d] = bf2f(((const u16*)edge)[ebase + (size_t)d * VW_ + w]);
        }
    } else {
        for (int f = tid; f < 3072; f += 384) {
            const int d = f / 24, w = f - d * 24;
            xs[w * 128 + d] = h2f(((const u16*)edge)[ebase + (size_t)d * VW_ + w]);
        }
    }
    const u16* W0 = DO_MSG ? We : W1;
    for (int f = tid; f < 16384; f += 384) {
        const int dj = f & 3, o_g = (f >> 2) & 31, oj = (f >> 7) & 3, dc = f >> 9;
        Wc[f] = W0[((o_g * 4 + oj) << 7) + (dc << 2) + dj];
    }
    if constexpr (DO_MSG) {
        for (int f = tid; f < 3072; f += 384) xw_s[f] = XW[(size_t)bt * N_ * 128 + f];
        if (tid < 128) mb_s[tid] = bf2f(msgb[tid]);
        if (tid < 24) gate_s[tid] = sigm(ADJ[rowbase + tid]);
    }
    if constexpr (DO_ADJ) {
        if (tid < 128) { b1_s[tid] = bf2f(b1[tid]); w2_s[tid] = bf2f(W2[tid]); }
    }
    __syncthreads();

    if constexpr (DO_MSG) {
        float acc[2][4];
        tile_gemm<2>(xs, Wc, og, rg, acc);
        const bool vvalid = v < nv;
        // overwrite valid cells of xs with gated messages (each thread touches
        // only rows of its own row-group; all reads done before writes)
#pragma unroll
        for (int r = 0; r < 2; ++r) {
            const int w = rg * 2 + r;
            if (vvalid && w < nv) {
#pragma unroll
                for (int oj = 0; oj < 4; ++oj) {
                    const int o = og * 4 + oj;
                    float m = xw_s[w * 128 + o] + acc[r][oj] + mb_s[o];
                    m = fmaxf(m, 0.0f);
                    xs[w * 128 + o] = gate_s[w] * m;
                }
            }
        }
        __syncthreads();
        if (tid < 128) {
            float s = 0.0f;
            if (vvalid)
                for (int w = 0; w < nv; ++w) s += xs[w * 128 + tid];
            MV[(size_t)blk * 128 + tid] = s;
        }
        if constexpr (DO_ADJ) {
            for (int f = tid; f < 16384; f += 384) {
                const int dj = f & 3, o_g = (f >> 2) & 31, oj = (f >> 7) & 3, dc = f >> 9;
                Wc[f] = W1[((o_g * 4 + oj) << 7) + (dc << 2) + dj];
            }
            __syncthreads();
        }
    }

    if constexpr (DO_ADJ) {
        float a2[2][4];
        tile_gemm<2>(xs, Wc, og, rg, a2);
        const float b2v = bf2f(b2[0]);
#pragma unroll
        for (int r = 0; r < 2; ++r) {
            float p = 0.0f;
#pragma unroll
            for (int oj = 0; oj < 4; ++oj) {
                const int o = og * 4 + oj;
                float h = a2[r][oj] + b1_s[o];
                h = fmaxf(h, 0.0f);
                p += h * w2_s[o];
            }
#pragma unroll
            for (int off = 16; off > 0; off >>= 1) p += __shfl_down(p, off);
            if (og == 0) ADJ[rowbase + rg * 2 + r] = p + b2v;
        }
    }
}

// ---------------------------------------------------------------------------
// Fused GRU: 32 nodes/block, 256 threads (4x4 tile). Per gate: stage Wih_g
// then Whh_g in LDS, accumulate, combine. Invalid nodes -> 0 (== node_resnet).
// ---------------------------------------------------------------------------
__global__ __launch_bounds__(256) void k_gru(
    const float* __restrict__ MV, const u16* __restrict__ Wih, const u16* __restrict__ Whh,
    const u16* __restrict__ bih, const u16* __restrict__ bhh,
    const int* __restrict__ nnr, float* __restrict__ HN) {
    __shared__ __align__(16) u16 Wc[16384];
    __shared__ __align__(16) float xs[32 * 128];
    __shared__ __align__(16) float hs[32 * 128];
    const int tid = threadIdx.x;
    const int og = tid & 31, rg = tid >> 5;   // rg 0..7
    const int node0 = blockIdx.x * 32;
    for (int f = tid; f < 4096; f += 256) {
        xs[f] = MV[(size_t)node0 * 128 + f];
        hs[f] = HN[(size_t)node0 * 128 + f];
    }
    float rr[4][4], zz[4][4], nn[4][4];
    for (int g = 0; g < 3; ++g) {
        float gi[4][4], gh[4][4];
        for (int half = 0; half < 2; ++half) {
            __syncthreads();   // protects Wc (and first-iter xs/hs staging)
            const u16* Wsrc = (half == 0 ? Wih : Whh) + g * 16384;
            for (int f = tid; f < 16384; f += 256) {
                const int dj = f & 3, o_g = (f >> 2) & 31, oj = (f >> 7) & 3, dc = f >> 9;
                Wc[f] = Wsrc[((o_g * 4 + oj) << 7) + (dc << 2) + dj];
            }
            __syncthreads();
            float a[4][4];
            tile_gemm<4>(half == 0 ? xs : hs, Wc, og, rg, a);
#pragma unroll
            for (int r = 0; r < 4; ++r)
#pragma unroll
                for (int oj = 0; oj < 4; ++oj) {
                    if (half == 0) gi[r][oj] = a[r][oj];
                    else           gh[r][oj] = a[r][oj];
                }
        }
#pragma unroll
        for (int r = 0; r < 4; ++r)
#pragma unroll
            for (int oj = 0; oj < 4; ++oj) {
                const int o = og * 4 + oj;
                const float giv = gi[r][oj] + bf2f(bih[g * 128 + o]);
                const float ghv = gh[r][oj] + bf2f(bhh[g * 128 + o]);
                if (g == 0) rr[r][oj] = sigm(giv + ghv);
                else if (g == 1) zz[r][oj] = sigm(giv + ghv);
                else nn[r][oj] = tanhf(giv + rr[r][oj] * ghv);
            }
    }
#pragma unroll
    for (int r = 0; r < 4; ++r) {
        const int row = rg * 4 + r;
        const int node = node0 + row;
        const int bt = node / N_, vv = node - bt * N_;
        const int nv = nnr[bt];
#pragma unroll
        for (int oj = 0; oj < 4; ++oj) {
            const int o = og * 4 + oj;
            const float h = hs[row * 128 + o];
            const float hv = (1.0f - zz[r][oj]) * nn[r][oj] + zz[r][oj] * h;
            HN[(size_t)node * 128 + o] = (vv < nv) ? hv : 0.0f;
        }
    }
}

// ---------------------------------------------------------------------------
// Recurrent LSTM with Whh in registers. 192 blocks (one per (b,n) row),
// 256 threads; thread owns gate outputs j and j+256 (64 u32 bf16-pairs each).
// GI holds x@Wih^T + both biases. h broadcast from LDS.
// ---------------------------------------------------------------------------
__global__ __launch_bounds__(256) void k_rec(const float* __restrict__ GI,
                                             const u16* __restrict__ WThh,
                                             float* __restrict__ OUTH) {
    __shared__ float h_s[128];
    __shared__ float g_s[512];
    const int tid = threadIdx.x;
    const int row = blockIdx.x;          // b*24+n
    const int bb = row / N_, nn = row - bb * N_;
    const u32* WT32 = (const u32*)WThh;  // WT32[k2*512 + j] = (Whh[j,2k2], Whh[j,2k2+1])
    u32 wa[64], wb[64];
#pragma unroll
    for (int k2 = 0; k2 < 64; ++k2) {
        wa[k2] = WT32[k2 * 512 + tid];
        wb[k2] = WT32[k2 * 512 + 256 + tid];
    }
    float c = 0.0f;
    if (tid < 128) h_s[tid] = 0.0f;
    __syncthreads();
    auto gbase = [&](int t) { return (size_t)((bb * T_ + t) * N_ + nn) * 512; };
    float ga = GI[gbase(0) + tid];
    float gb = GI[gbase(0) + 256 + tid];
    for (int t = 0; t < T_; ++t) {
        float na = 0.0f, nb = 0.0f;
        if (t + 1 < T_) {
            na = GI[gbase(t + 1) + tid];
            nb = GI[gbase(t + 1) + 256 + tid];
        }
        float acc0 = 0.0f, acc1 = 0.0f;
#pragma unroll
        for (int k2 = 0; k2 < 64; ++k2) {
            const float2 h2 = *(const float2*)&h_s[k2 * 2];
            const u32 A = wa[k2], Bv = wb[k2];
            acc0 = fmaf(bits2f(A << 16), h2.x, fmaf(bits2f(A & 0xFFFF0000u), h2.y, acc0));
            acc1 = fmaf(bits2f(Bv << 16), h2.x, fmaf(bits2f(Bv & 0xFFFF0000u), h2.y, acc1));
        }
        g_s[tid] = ga + acc0;
        g_s[tid + 256] = gb + acc1;
        __syncthreads();
        if (tid < 128) {
            const float gi = g_s[tid], gf = g_s[128 + tid];
            const float gg = g_s[256 + tid], go = g_s[384 + tid];
            c = sigm(gf) * c + sigm(gi) * tanhf(gg);
            const float hv = sigm(go) * tanhf(c);
            h_s[tid] = hv;
            OUTH[((size_t)t * 192 + row) * 128 + tid] = hv;
        }
        __syncthreads();
        ga = na; gb = nb;
    }
}

// ---------------------------------------------------------------------------
// Readout: out[b,t,n,c] = mask ? OUTH_row . ro_W[c] + ro_b[c] : 0
// ---------------------------------------------------------------------------
__global__ __launch_bounds__(256) void k_readout(const float* __restrict__ OUTH, const u16* __restrict__ roW,
                                                 const u16* __restrict__ rob, const int* __restrict__ nnr,
                                                 void* __restrict__ out, const int* __restrict__ flag) {
    const int idx = blockIdx.x * 256 + threadIdx.x;
    const int btn = idx / C_, c = idx - btn * C_;
    const int bt = btn / N_, n = btn - bt * N_;
    const int b = bt / T_, t = bt - b * T_;
    const int nv = nnr[bt];
    float val = 0.0f;
    if (n < nv) {
        const float* hrow = OUTH + ((size_t)t * 192 + b * N_ + n) * 128;
        float acc = bf2f(rob[c]);
        for (int k = 0; k < 128; ++k) acc += bf2f(roW[c * 128 + k]) * hrow[k];
        val = acc;
    }
    const int flg = flag[0];
    if (flg == 1) ((float*)out)[idx] = val;
    else if (flg == 0) ((u16*)out)[idx] = f2bf(val);
    else { __half h = __float2half(val); u16 b16; __builtin_memcpy(&b16, &h, 2); ((u16*)out)[idx] = b16; }
}

// ---------------------------------------------------------------------------
extern "C" void kernel_launch(void* const* d_in, const int* in_sizes, int n_in,
                              void* d_out, int out_size, void* d_ws, size_t ws_size,
                              hipStream_t stream) {
    const void* node = d_in[0];
    const void* edge = d_in[1];
    const int* nnr = (const int*)d_in[19];

    // Workspace layout (~23.5 MB)
    char* ws = (char*)d_ws;
    int* dflag = (int*)ws;    ws += 16;
    float* HN = (float*)ws;   ws += (size_t)BTN_ * D_ * 4;    // 3.15 MB
    float* XW = (float*)ws;   ws += (size_t)BTN_ * D_ * 4;    // 3.15 MB
    float* MV = (float*)ws;   ws += (size_t)BTN_ * D_ * 4;    // 3.15 MB
    float* ADJ = (float*)ws;  ws += (size_t)BTVW_ * 4;        // 0.59 MB
    float* GI = (float*)ws;   ws += (size_t)BTN_ * 512 * 4;   // 12.58 MB
    u16* WThh = (u16*)ws;     ws += 65536 * 2;                // 0.13 MB
    float* OUTH = XW;         // XW dead after last k_edge; same size

    // Canonical bf16 weight arrays
    u16* cbase = (u16*)ws;
    const int cvtN[17] = {16384, 128, 128, 1, 16384, 16384, 128,
                          49152, 49152, 384, 384, 65536, 65536, 512, 512, 768, 6};
    CvtArgs ca;
    u16* cptr[17];
    {
        int off = 0;
        for (int i = 0; i < 17; ++i) {
            cptr[i] = cbase + off;
            ca.src[i] = d_in[2 + i];
            ca.dst[i] = cptr[i];
            ca.start[i] = off ? 0 : 0;  // placeholder, fixed below
            off += (cvtN[i] + 7) & ~7;
        }
        int cum = 0;
        for (int i = 0; i < 17; ++i) { ca.start[i] = cum; cum += cvtN[i]; }
        ca.start[17] = cum;             // 281479
    }
    u16* cW1 = cptr[0];  u16* cb1 = cptr[1];  u16* cW2 = cptr[2];  u16* cb2 = cptr[3];
    u16* cWh = cptr[4];  u16* cWe = cptr[5];  u16* cmb = cptr[6];
    u16* cgWih = cptr[7]; u16* cgWhh = cptr[8]; u16* cgbih = cptr[9]; u16* cgbhh = cptr[10];
    u16* clsWih = cptr[11]; u16* clsWhh = cptr[12]; u16* clsbih = cptr[13]; u16* clsbhh = cptr[14];
    u16* croW = cptr[15]; u16* crob = cptr[16];

    // 1. detect input float dtype
    k_detect<<<1, 256, 0, stream>>>(node, nnr, dflag);
    // 2. canonicalize all weights to bf16 in ONE launch
    k_convall<<<(281479 + 255) / 256, 256, 0, stream>>>(ca, dflag);
    // 3. node transpose -> fp32 HN; LSTM Whh transpose
    k_transpose_node<<<BT_, 256, 0, stream>>>(node, HN, dflag);
    k_wtprep<<<256, 256, 0, stream>>>(clsWhh, WThh);
    // 4. layer-0 adjacency logits from raw edge features
    k_edge<false, true><<<BTVW_ / VW_ * N_, 384, 0, stream>>>(edge, dflag, XW, cWe, cmb,
                                                              cW1, cb1, cW2, cb2, nnr, ADJ, MV);
    for (int l = 0; l < P_; ++l) {
        k_xw<<<192, 256, 0, stream>>>(HN, cWh, XW);
        if (l < P_ - 1)
            k_edge<true, true><<<BTN_, 384, 0, stream>>>(edge, dflag, XW, cWe, cmb, cW1, cb1,
                                                         cW2, cb2, nnr, ADJ, MV);
        else
            k_edge<true, false><<<BTN_, 384, 0, stream>>>(edge, dflag, XW, cWe, cmb, cW1, cb1,
                                                          cW2, cb2, nnr, ADJ, MV);
        k_gru<<<192, 256, 0, stream>>>(MV, cgWih, cgWhh, cgbih, cgbhh, nnr, HN);
    }
    // 5. LSTM: batched input GEMM + register-resident recurrence
    k_gi<<<dim3(192, 4), 256, 0, stream>>>(HN, clsWih, clsbih, clsbhh, GI);
    k_rec<<<192, 256, 0, stream>>>(GI, WThh, OUTH);
    k_readout<<<144, 256, 0, stream>>>(OUTH, croW, crob, nnr, d_out, dflag);
}

// Round 6
// 702.764 us; speedup vs baseline: 2.4545x; 2.4545x over previous
//
#include <hip/hip_runtime.h>
#include <hip/hip_fp16.h>
#include <cmath>

typedef unsigned short u16;
typedef unsigned int   u32;
typedef short bf16x8 __attribute__((ext_vector_type(8)));
typedef float f32x4 __attribute__((ext_vector_type(4)));

// Problem constants
constexpr int B_ = 8, T_ = 32, N_ = 24, D_ = 128;
constexpr int BT_ = B_ * T_;            // 256
constexpr int VW_ = N_ * N_;            // 576
constexpr int BTN_ = BT_ * N_;          // 6144
constexpr int BTVW_ = BT_ * VW_;        // 147456
constexpr int P_ = 3;
constexpr int C_ = 6;
constexpr int SA_ = 136;                // padded A-tile row stride (u16)

__device__ __forceinline__ float bits2f(u32 u) { float f; __builtin_memcpy(&f, &u, 4); return f; }
__device__ __forceinline__ float bf2f(u16 h) { return bits2f(((u32)h) << 16); }
__device__ __forceinline__ u16 f2bf(float f) {
    u32 u; __builtin_memcpy(&u, &f, 4);
    u32 r = u + 0x7FFFu + ((u >> 16) & 1u);
    return (u16)(r >> 16);
}
__device__ __forceinline__ float h2f(u16 b) {
    __half h; __builtin_memcpy(&h, &b, 2);
    return __half2float(h);
}
__device__ __forceinline__ float sigm(float x) { return 1.0f / (1.0f + expf(-x)); }

// flag: 0 = bf16, 1 = fp32, 2 = fp16
__device__ __forceinline__ float ldany(const void* p, size_t i, int flg) {
    if (flg == 1) return ((const float*)p)[i];
    if (flg == 0) return bf2f(((const u16*)p)[i]);
    return h2f(((const u16*)p)[i]);
}

// ---------------------------------------------------------------------------
// Dtype detection: node_resnet [bt,d,n] has zeros exactly at n >= nnr[bt].
// ---------------------------------------------------------------------------
__global__ __launch_bounds__(256) void k_detect(const void* __restrict__ node,
                                                const int* __restrict__ nnr,
                                                int* __restrict__ flag) {
    __shared__ int sc[3];
    const int tid = threadIdx.x;
    if (tid < 3) sc[tid] = 0;
    __syncthreads();
    int loc0 = 0, loc1 = 0, loc2 = 0;
    for (int c = tid; c < 768; c += 256) {
        const int bt = c / 96, rem = c % 96;
        const int d = rem / 24, n = rem % 24;
        const bool ez = (n >= nnr[bt]);
        const size_t i = (size_t)bt * 3072 + d * 24 + n;
        {
            const float v = bf2f(((const u16*)node)[i]);
            loc0 += (ez ? (v == 0.0f) : (v != 0.0f && fabsf(v) < 100.0f)) ? 1 : 0;
        }
        {
            const float v = ((const float*)node)[i];
            loc1 += (isfinite(v) && (ez ? (v == 0.0f) : (v != 0.0f && fabsf(v) < 100.0f))) ? 1 : 0;
        }
        {
            const float v = h2f(((const u16*)node)[i]);
            loc2 += (isfinite(v) && (ez ? (v == 0.0f) : (v != 0.0f && fabsf(v) < 100.0f))) ? 1 : 0;
        }
    }
    atomicAdd(&sc[0], loc0);
    atomicAdd(&sc[1], loc1);
    atomicAdd(&sc[2], loc2);
    __syncthreads();
    if (tid == 0) {
        int f = 0, best = sc[0];
        if (sc[1] > best) { f = 1; best = sc[1]; }
        if (sc[2] > best) { f = 2; }
        flag[0] = f;
    }
}

// ---------------------------------------------------------------------------
// Canonicalize ALL weight/bias arrays to bf16 in one launch.
// ---------------------------------------------------------------------------
struct CvtArgs {
    const void* src[17];
    u16* dst[17];
    int start[18];
};

__global__ __launch_bounds__(256) void k_convall(CvtArgs a, const int* __restrict__ flag) {
    const int idx = blockIdx.x * 256 + threadIdx.x;
    if (idx >= a.start[17]) return;
    int s = 0;
#pragma unroll
    for (int i = 1; i < 17; ++i) s += (idx >= a.start[i]) ? 1 : 0;
    const int off = idx - a.start[s];
    const int flg = flag[0];
    u16 v;
    if (flg == 0) v = ((const u16*)a.src[s])[off];
    else if (flg == 1) v = f2bf(((const float*)a.src[s])[off]);
    else v = f2bf(h2f(((const u16*)a.src[s])[off]));
    a.dst[s][off] = v;
}

// Shared register-tile GEMM over K=128 (VALU path, used by k_xw/k_gi/k_gru).
template <int R>
__device__ __forceinline__ void tile_gemm(const float* xs, const u16* Wc,
                                          int og, int rg, float acc[R][4]) {
#pragma unroll
    for (int r = 0; r < R; ++r)
#pragma unroll
        for (int oj = 0; oj < 4; ++oj) acc[r][oj] = 0.0f;
    for (int dc = 0; dc < 32; ++dc) {
        float4 xv[R];
#pragma unroll
        for (int r = 0; r < R; ++r) xv[r] = *(const float4*)&xs[(rg * R + r) * 128 + dc * 4];
#pragma unroll
        for (int oj = 0; oj < 4; ++oj) {
            const uint2 wu = *(const uint2*)&Wc[dc * 512 + oj * 128 + og * 4];
            const float w0 = bits2f(wu.x << 16), w1 = bits2f(wu.x & 0xFFFF0000u);
            const float w2f = bits2f(wu.y << 16), w3 = bits2f(wu.y & 0xFFFF0000u);
#pragma unroll
            for (int r = 0; r < R; ++r)
                acc[r][oj] = fmaf(xv[r].w, w3,
                             fmaf(xv[r].z, w2f,
                             fmaf(xv[r].y, w1,
                             fmaf(xv[r].x, w0, acc[r][oj]))));
        }
    }
}

// ---------------------------------------------------------------------------
// Transpose node_resnet [bt, d, n] -> HN [bt, n, d] fp32. grid = BT_
// ---------------------------------------------------------------------------
__global__ __launch_bounds__(256) void k_transpose_node(const void* __restrict__ node,
                                                        float* __restrict__ HN,
                                                        const int* __restrict__ flag) {
    const int bt = blockIdx.x;
    const int flg = flag[0];
    for (int f = threadIdx.x; f < 3072; f += 256) {
        const int d = f / 24, n = f - d * 24;
        HN[(size_t)bt * 3072 + n * 128 + d] = ldany(node, (size_t)bt * 3072 + f, flg);
    }
}

// ---------------------------------------------------------------------------
// Edge transpose: edge [bt, d, vw] -> EB [bt*576+vw][d] bf16. 32x32 tiles.
// grid = BT_ * 72 (4 d-tiles x 18 vw-tiles)
// ---------------------------------------------------------------------------
__global__ __launch_bounds__(256) void k_eb(const void* __restrict__ edge,
                                            u16* __restrict__ EB,
                                            const int* __restrict__ flag) {
    __shared__ float t[32][33];
    const int bt = blockIdx.x / 72;
    const int tile = blockIdx.x % 72;
    const int d0 = (tile / 18) * 32, vw0 = (tile % 18) * 32;
    const int tx = threadIdx.x & 31, ty = threadIdx.x >> 5;
    const int flg = flag[0];
    const size_t sbase = (size_t)bt * D_ * VW_;
#pragma unroll
    for (int r = 0; r < 4; ++r) {
        const int dr = ty * 4 + r;
        t[d0 == d0 ? dr : dr][tx] = ldany(edge, sbase + (size_t)(d0 + dr) * VW_ + vw0 + tx, flg);
    }
    __syncthreads();
#pragma unroll
    for (int r = 0; r < 4; ++r) {
        const int vr = ty * 4 + r;
        EB[((size_t)bt * VW_ + vw0 + vr) * 128 + d0 + tx] = f2bf(t[tx][vr]);
    }
}

// ---------------------------------------------------------------------------
// LSTM Whh transpose: WT[kk*1024 + j*2 + p] = Whh[j*128 + kk*2 + p]  (bf16)
// ---------------------------------------------------------------------------
__global__ __launch_bounds__(256) void k_wtprep(const u16* __restrict__ Whh,
                                                u16* __restrict__ WThh) {
    const int idx = blockIdx.x * 256 + threadIdx.x;
    const int kk = idx >> 10;
    const int rem = idx & 1023;
    const int j = rem >> 1, p = rem & 1;
    WThh[idx] = Whh[j * 128 + kk * 2 + p];
}

// ---------------------------------------------------------------------------
// ME = EB @ We^T via MFMA. 64 rows/block (4 waves x 16), A direct from global.
// grid = 2304, 256 threads. Output bf16.
// ---------------------------------------------------------------------------
__global__ __launch_bounds__(256) void k_me(const u16* __restrict__ EB,
                                            const u16* __restrict__ We,
                                            u16* __restrict__ ME) {
    const int tid = threadIdx.x;
    const int wv = tid >> 6, lane = tid & 63;
    const int m = lane & 15, quad = lane >> 4;
    const int r0 = blockIdx.x * 64 + wv * 16;
    bf16x8 a[4];
#pragma unroll
    for (int ks = 0; ks < 4; ++ks)
        a[ks] = *(const bf16x8*)&EB[(size_t)(r0 + m) * 128 + ks * 32 + quad * 8];
    f32x4 acc[8];
    const f32x4 z = {0.f, 0.f, 0.f, 0.f};
#pragma unroll
    for (int ct = 0; ct < 8; ++ct) acc[ct] = z;
#pragma unroll
    for (int ct = 0; ct < 8; ++ct) {
        const int n = ct * 16 + m;
#pragma unroll
        for (int ks = 0; ks < 4; ++ks) {
            const bf16x8 b = *(const bf16x8*)&We[n * 128 + ks * 32 + quad * 8];
            acc[ct] = __builtin_amdgcn_mfma_f32_16x16x32_bf16(a[ks], b, acc[ct], 0, 0, 0);
        }
    }
#pragma unroll
    for (int ct = 0; ct < 8; ++ct)
#pragma unroll
        for (int reg = 0; reg < 4; ++reg)
            ME[(size_t)(r0 + quad * 4 + reg) * 128 + ct * 16 + m] = f2bf(acc[ct][reg]);
}

// ---------------------------------------------------------------------------
// Fused per-(bt, v-pair) edge kernel. 48 edge rows/block (2 groups of 24).
//  MSG:  build h_edge rows (gate*relu(XW+ME+mb), 0 for invalid -- edge_resnet
//        is 0 exactly where pair_mask is false) + MV accumulated in fp32.
//  !MSG: A-tile = raw EB rows (layer-0 adjacency).
//  ADJP: link-MLP via MFMA on A-tile -> ADJ in place.
// 256 threads; waves 0..2 do MFMA (16 rows each), wave 3 helps build only.
// ---------------------------------------------------------------------------
template <bool MSG, bool ADJP>
__global__ __launch_bounds__(256) void k_fused(
    const u16* __restrict__ EB, const u16* __restrict__ ME,
    const float* __restrict__ XW, const u16* __restrict__ mb,
    const u16* __restrict__ W1, const u16* __restrict__ b1,
    const u16* __restrict__ W2, const u16* __restrict__ b2,
    const int* __restrict__ nnr, float* __restrict__ ADJ,
    float* __restrict__ MV) {
    __shared__ __align__(16) u16 A[48 * SA_];
    __shared__ float gate_s[48];
    __shared__ float mb_s[128];
    const int tid = threadIdx.x;
    const int blk = blockIdx.x;
    const int bt = blk / 12, pr = blk - bt * 12;
    const int v0 = pr * 2;
    const int e0 = bt * VW_ + v0 * N_;
    const int nv = nnr[bt];

    if constexpr (MSG) {
        if (tid < 48) gate_s[tid] = sigm(ADJ[e0 + tid]);
        if (tid < 128) mb_s[tid] = bf2f(mb[tid]);
        __syncthreads();
        const int grp = tid >> 7, o = tid & 127;
        const int v = v0 + grp;
        float mv = 0.0f;
        for (int w = 0; w < N_; ++w) {
            const int rr = grp * 24 + w;
            float val = 0.0f;
            if (v < nv && w < nv) {
                const float me = bf2f(ME[(size_t)(e0 + rr) * 128 + o]);
                float mm = XW[(size_t)(bt * N_ + w) * 128 + o] + me + mb_s[o];
                val = gate_s[rr] * fmaxf(mm, 0.0f);
                mv += val;
            }
            if (ADJP) A[rr * SA_ + o] = f2bf(val);
        }
        MV[(size_t)(bt * N_ + v) * 128 + o] = mv;
    } else {
        for (int f = tid; f < 6144; f += 256) {
            const int rr = f >> 7, o = f & 127;
            A[rr * SA_ + o] = EB[(size_t)(e0 + rr) * 128 + o];
        }
    }

    if constexpr (ADJP) {
        __syncthreads();
        if (tid >= 192) return;
        const int wv = tid >> 6, lane = tid & 63;
        const int m = lane & 15, quad = lane >> 4;
        bf16x8 a[4];
#pragma unroll
        for (int ks = 0; ks < 4; ++ks)
            a[ks] = *(const bf16x8*)&A[(wv * 16 + m) * SA_ + ks * 32 + quad * 8];
        f32x4 acc[8];
        const f32x4 z = {0.f, 0.f, 0.f, 0.f};
#pragma unroll
        for (int ct = 0; ct < 8; ++ct) acc[ct] = z;
#pragma unroll
        for (int ct = 0; ct < 8; ++ct) {
            const int n = ct * 16 + m;
#pragma unroll
            for (int ks = 0; ks < 4; ++ks) {
                const bf16x8 b = *(const bf16x8*)&W1[n * 128 + ks * 32 + quad * 8];
                acc[ct] = __builtin_amdgcn_mfma_f32_16x16x32_bf16(a[ks], b, acc[ct], 0, 0, 0);
            }
        }
        const float b2v = bf2f(b2[0]);
        float p[4] = {0.f, 0.f, 0.f, 0.f};
#pragma unroll
        for (int ct = 0; ct < 8; ++ct) {
            const int n = ct * 16 + m;
            const float b1v = bf2f(b1[n]);
            const float w2v = bf2f(W2[n]);
#pragma unroll
            for (int reg = 0; reg < 4; ++reg)
                p[reg] += fmaxf(acc[ct][reg] + b1v, 0.0f) * w2v;
        }
#pragma unroll
        for (int reg = 0; reg < 4; ++reg) {
            p[reg] += __shfl_xor(p[reg], 1);
            p[reg] += __shfl_xor(p[reg], 2);
            p[reg] += __shfl_xor(p[reg], 4);
            p[reg] += __shfl_xor(p[reg], 8);
        }
        if (m == 0) {
#pragma unroll
            for (int reg = 0; reg < 4; ++reg)
                ADJ[e0 + wv * 16 + quad * 4 + reg] = p[reg] + b2v;
        }
    }
}

// ---------------------------------------------------------------------------
// XW = msg_Wh @ h_node. 192 blocks x 32 rows, 256 threads (4x4 tiles).
// ---------------------------------------------------------------------------
__global__ __launch_bounds__(256) void k_xw(const float* __restrict__ HN, const u16* __restrict__ W,
                                            float* __restrict__ XW) {
    __shared__ __align__(16) u16 Wc[16384];
    __shared__ __align__(16) float xs[4096];
    const int tid = threadIdx.x;
    const int og = tid & 31, rg = tid >> 5;
    for (int f = tid; f < 16384; f += 256) {
        const int dj = f & 3, o_g = (f >> 2) & 31, oj = (f >> 7) & 3, dc = f >> 9;
        Wc[f] = W[((o_g * 4 + oj) << 7) + (dc << 2) + dj];
    }
    const int rowBase = blockIdx.x * 32;
    for (int f = tid; f < 4096; f += 256) xs[f] = HN[(size_t)rowBase * 128 + f];
    __syncthreads();
    float acc[4][4];
    tile_gemm<4>(xs, Wc, og, rg, acc);
#pragma unroll
    for (int r = 0; r < 4; ++r) {
        const int row = rowBase + rg * 4 + r;
        float4 o4;
        o4.x = acc[r][0]; o4.y = acc[r][1]; o4.z = acc[r][2]; o4.w = acc[r][3];
        *(float4*)&XW[(size_t)row * 128 + og * 4] = o4;
    }
}

// ---------------------------------------------------------------------------
// GI = h_node @ lstm_Wih^T + (bih + bhh). grid dim3(192, 4), 256 threads.
// ---------------------------------------------------------------------------
__global__ __launch_bounds__(256) void k_gi(const float* __restrict__ HN, const u16* __restrict__ W,
                                            const u16* __restrict__ bih, const u16* __restrict__ bhh,
                                            float* __restrict__ GI) {
    __shared__ __align__(16) u16 Wc[16384];
    __shared__ __align__(16) float xs[4096];
    __shared__ float bias_s[128];
    const int tid = threadIdx.x;
    const int og = tid & 31, rg = tid >> 5;
    const u16* Wp = W + (size_t)blockIdx.y * 16384;
    const int ocol = blockIdx.y * 128;
    for (int f = tid; f < 16384; f += 256) {
        const int dj = f & 3, o_g = (f >> 2) & 31, oj = (f >> 7) & 3, dc = f >> 9;
        Wc[f] = Wp[((o_g * 4 + oj) << 7) + (dc << 2) + dj];
    }
    if (tid < 128) bias_s[tid] = bf2f(bih[ocol + tid]) + bf2f(bhh[ocol + tid]);
    const int rowBase = blockIdx.x * 32;
    for (int f = tid; f < 4096; f += 256) xs[f] = HN[(size_t)rowBase * 128 + f];
    __syncthreads();
    float acc[4][4];
    tile_gemm<4>(xs, Wc, og, rg, acc);
#pragma unroll
    for (int r = 0; r < 4; ++r) {
        const int row = rowBase + rg * 4 + r;
        float4 o4;
        o4.x = acc[r][0] + bias_s[og * 4 + 0];
        o4.y = acc[r][1] + bias_s[og * 4 + 1];
        o4.z = acc[r][2] + bias_s[og * 4 + 2];
        o4.w = acc[r][3] + bias_s[og * 4 + 3];
        *(float4*)&GI[(size_t)row * 512 + ocol + og * 4] = o4;
    }
}

// ---------------------------------------------------------------------------
// Fused GRU: 32 nodes/block, 256 threads (4x4 tile).
// ---------------------------------------------------------------------------
__global__ __launch_bounds__(256) void k_gru(
    const float* __restrict__ MV, const u16* __restrict__ Wih, const u16* __restrict__ Whh,
    const u16* __restrict__ bih, const u16* __restrict__ bhh,
    const int* __restrict__ nnr, float* __restrict__ HN) {
    __shared__ __align__(16) u16 Wc[16384];
    __shared__ __align__(16) float xs[32 * 128];
    __shared__ __align__(16) float hs[32 * 128];
    const int tid = threadIdx.x;
    const int og = tid & 31, rg = tid >> 5;
    const int node0 = blockIdx.x * 32;
    for (int f = tid; f < 4096; f += 256) {
        xs[f] = MV[(size_t)node0 * 128 + f];
        hs[f] = HN[(size_t)node0 * 128 + f];
    }
    float rr[4][4], zz[4][4], nn[4][4];
    for (int g = 0; g < 3; ++g) {
        float gi[4][4], gh[4][4];
        for (int half = 0; half < 2; ++half) {
            __syncthreads();
            const u16* Wsrc = (half == 0 ? Wih : Whh) + g * 16384;
            for (int f = tid; f < 16384; f += 256) {
                const int dj = f & 3, o_g = (f >> 2) & 31, oj = (f >> 7) & 3, dc = f >> 9;
                Wc[f] = Wsrc[((o_g * 4 + oj) << 7) + (dc << 2) + dj];
            }
            __syncthreads();
            float a[4][4];
            tile_gemm<4>(half == 0 ? xs : hs, Wc, og, rg, a);
#pragma unroll
            for (int r = 0; r < 4; ++r)
#pragma unroll
                for (int oj = 0; oj < 4; ++oj) {
                    if (half == 0) gi[r][oj] = a[r][oj];
                    else           gh[r][oj] = a[r][oj];
                }
        }
#pragma unroll
        for (int r = 0; r < 4; ++r)
#pragma unroll
            for (int oj = 0; oj < 4; ++oj) {
                const int o = og * 4 + oj;
                const float giv = gi[r][oj] + bf2f(bih[g * 128 + o]);
                const float ghv = gh[r][oj] + bf2f(bhh[g * 128 + o]);
                if (g == 0) rr[r][oj] = sigm(giv + ghv);
                else if (g == 1) zz[r][oj] = sigm(giv + ghv);
                else nn[r][oj] = tanhf(giv + rr[r][oj] * ghv);
            }
    }
#pragma unroll
    for (int r = 0; r < 4; ++r) {
        const int row = rg * 4 + r;
        const int node = node0 + row;
        const int bt = node / N_, vv = node - bt * N_;
        const int nv = nnr[bt];
#pragma unroll
        for (int oj = 0; oj < 4; ++oj) {
            const int o = og * 4 + oj;
            const float h = hs[row * 128 + o];
            const float hv = (1.0f - zz[r][oj]) * nn[r][oj] + zz[r][oj] * h;
            HN[(size_t)node * 128 + o] = (vv < nv) ? hv : 0.0f;
        }
    }
}

// ---------------------------------------------------------------------------
// Recurrent LSTM with Whh in registers. 192 blocks, 256 threads.
// ---------------------------------------------------------------------------
__global__ __launch_bounds__(256) void k_rec(const float* __restrict__ GI,
                                             const u16* __restrict__ WThh,
                                             float* __restrict__ OUTH) {
    __shared__ float h_s[128];
    __shared__ float g_s[512];
    const int tid = threadIdx.x;
    const int row = blockIdx.x;          // b*24+n
    const int bb = row / N_, nn = row - bb * N_;
    const u32* WT32 = (const u32*)WThh;
    u32 wa[64], wb[64];
#pragma unroll
    for (int k2 = 0; k2 < 64; ++k2) {
        wa[k2] = WT32[k2 * 512 + tid];
        wb[k2] = WT32[k2 * 512 + 256 + tid];
    }
    float c = 0.0f;
    if (tid < 128) h_s[tid] = 0.0f;
    __syncthreads();
    auto gbase = [&](int t) { return (size_t)((bb * T_ + t) * N_ + nn) * 512; };
    float ga = GI[gbase(0) + tid];
    float gb = GI[gbase(0) + 256 + tid];
    for (int t = 0; t < T_; ++t) {
        float na = 0.0f, nb = 0.0f;
        if (t + 1 < T_) {
            na = GI[gbase(t + 1) + tid];
            nb = GI[gbase(t + 1) + 256 + tid];
        }
        float acc0 = 0.0f, acc1 = 0.0f;
#pragma unroll
        for (int k2 = 0; k2 < 64; ++k2) {
            const float2 h2 = *(const float2*)&h_s[k2 * 2];
            const u32 A = wa[k2], Bv = wb[k2];
            acc0 = fmaf(bits2f(A << 16), h2.x, fmaf(bits2f(A & 0xFFFF0000u), h2.y, acc0));
            acc1 = fmaf(bits2f(Bv << 16), h2.x, fmaf(bits2f(Bv & 0xFFFF0000u), h2.y, acc1));
        }
        g_s[tid] = ga + acc0;
        g_s[tid + 256] = gb + acc1;
        __syncthreads();
        if (tid < 128) {
            const float gi = g_s[tid], gf = g_s[128 + tid];
            const float gg = g_s[256 + tid], go = g_s[384 + tid];
            c = sigm(gf) * c + sigm(gi) * tanhf(gg);
            const float hv = sigm(go) * tanhf(c);
            h_s[tid] = hv;
            OUTH[((size_t)t * 192 + row) * 128 + tid] = hv;
        }
        __syncthreads();
        ga = na; gb = nb;
    }
}

// ---------------------------------------------------------------------------
// Readout: out[b,t,n,c] = mask ? OUTH_row . ro_W[c] + ro_b[c] : 0
// ---------------------------------------------------------------------------
__global__ __launch_bounds__(256) void k_readout(const float* __restrict__ OUTH, const u16* __restrict__ roW,
                                                 const u16* __restrict__ rob, const int* __restrict__ nnr,
                                                 void* __restrict__ out, const int* __restrict__ flag) {
    const int idx = blockIdx.x * 256 + threadIdx.x;
    const int btn = idx / C_, c = idx - btn * C_;
    const int bt = btn / N_, n = btn - bt * N_;
    const int b = bt / T_, t = bt - b * T_;
    const int nv = nnr[bt];
    float val = 0.0f;
    if (n < nv) {
        const float* hrow = OUTH + ((size_t)t * 192 + b * N_ + n) * 128;
        float acc = bf2f(rob[c]);
        for (int k = 0; k < 128; ++k) acc += bf2f(roW[c * 128 + k]) * hrow[k];
        val = acc;
    }
    const int flg = flag[0];
    if (flg == 1) ((float*)out)[idx] = val;
    else if (flg == 0) ((u16*)out)[idx] = f2bf(val);
    else { __half h = __float2half(val); u16 b16; __builtin_memcpy(&b16, &h, 2); ((u16*)out)[idx] = b16; }
}

// ---------------------------------------------------------------------------
extern "C" void kernel_launch(void* const* d_in, const int* in_sizes, int n_in,
                              void* d_out, int out_size, void* d_ws, size_t ws_size,
                              hipStream_t stream) {
    const void* node = d_in[0];
    const void* edge = d_in[1];
    const int* nnr = (const int*)d_in[19];

    // Workspace layout (~99 MB)
    char* ws = (char*)d_ws;
    int* dflag = (int*)ws;    ws += 16;
    float* HN = (float*)ws;   ws += (size_t)BTN_ * D_ * 4;    // 3.15 MB
    float* XW = (float*)ws;   ws += (size_t)BTN_ * D_ * 4;    // 3.15 MB
    float* MV = (float*)ws;   ws += (size_t)BTN_ * D_ * 4;    // 3.15 MB
    float* ADJ = (float*)ws;  ws += (size_t)BTVW_ * 4;        // 0.59 MB
    float* GI = (float*)ws;   ws += (size_t)BTN_ * 512 * 4;   // 12.58 MB
    u16* WThh = (u16*)ws;     ws += 65536 * 2;                // 0.13 MB
    u16* EB = (u16*)ws;       ws += (size_t)BTVW_ * D_ * 2;   // 37.75 MB
    u16* ME = (u16*)ws;       ws += (size_t)BTVW_ * D_ * 2;   // 37.75 MB
    float* OUTH = XW;         // XW dead after last k_fused; same size

    // Canonical bf16 weight arrays
    u16* cbase = (u16*)ws;
    const int cvtN[17] = {16384, 128, 128, 1, 16384, 16384, 128,
                          49152, 49152, 384, 384, 65536, 65536, 512, 512, 768, 6};
    CvtArgs ca;
    u16* cptr[17];
    {
        int off = 0;
        for (int i = 0; i < 17; ++i) {
            cptr[i] = cbase + off;
            ca.src[i] = d_in[2 + i];
            ca.dst[i] = cptr[i];
            off += (cvtN[i] + 7) & ~7;
        }
        int cum = 0;
        for (int i = 0; i < 17; ++i) { ca.start[i] = cum; cum += cvtN[i]; }
        ca.start[17] = cum;             // 281479
    }
    u16* cW1 = cptr[0];  u16* cb1 = cptr[1];  u16* cW2 = cptr[2];  u16* cb2 = cptr[3];
    u16* cWh = cptr[4];  u16* cWe = cptr[5];  u16* cmb = cptr[6];
    u16* cgWih = cptr[7]; u16* cgWhh = cptr[8]; u16* cgbih = cptr[9]; u16* cgbhh = cptr[10];
    u16* clsWih = cptr[11]; u16* clsWhh = cptr[12]; u16* clsbih = cptr[13]; u16* clsbhh = cptr[14];
    u16* croW = cptr[15]; u16* crob = cptr[16];

    k_detect<<<1, 256, 0, stream>>>(node, nnr, dflag);
    k_convall<<<(281479 + 255) / 256, 256, 0, stream>>>(ca, dflag);
    k_transpose_node<<<BT_, 256, 0, stream>>>(node, HN, dflag);
    k_wtprep<<<256, 256, 0, stream>>>(clsWhh, WThh);
    k_eb<<<BT_ * 72, 256, 0, stream>>>(edge, EB, dflag);
    k_me<<<BTVW_ / 64, 256, 0, stream>>>(EB, cWe, ME);
    // layer-0 adjacency logits from raw edge rows (MFMA link-MLP)
    k_fused<false, true><<<BTN_ / 2, 256, 0, stream>>>(EB, ME, XW, cmb, cW1, cb1, cW2, cb2,
                                                       nnr, ADJ, MV);
    for (int l = 0; l < P_; ++l) {
        k_xw<<<192, 256, 0, stream>>>(HN, cWh, XW);
        if (l < P_ - 1)
            k_fused<true, true><<<BTN_ / 2, 256, 0, stream>>>(EB, ME, XW, cmb, cW1, cb1, cW2, cb2,
                                                              nnr, ADJ, MV);
        else
            k_fused<true, false><<<BTN_ / 2, 256, 0, stream>>>(EB, ME, XW, cmb, cW1, cb1, cW2, cb2,
                                                               nnr, ADJ, MV);
        k_gru<<<192, 256, 0, stream>>>(MV, cgWih, cgWhh, cgbih, cgbhh, nnr, HN);
    }
    k_gi<<<dim3(192, 4), 256, 0, stream>>>(HN, clsWih, clsbih, clsbhh, GI);
    k_rec<<<192, 256, 0, stream>>>(GI, WThh, OUTH);
    k_readout<<<144, 256, 0, stream>>>(OUTH, croW, crob, nnr, d_out, dflag);
}

// Round 8
// 541.101 us; speedup vs baseline: 3.1878x; 1.2988x over previous
//
#include <hip/hip_runtime.h>
#include <cmath>

typedef unsigned short u16;
typedef unsigned int   u32;
typedef short bf16x8 __attribute__((ext_vector_type(8)));
typedef float f32x4 __attribute__((ext_vector_type(4)));

// Problem constants
constexpr int B_ = 8, T_ = 32, N_ = 24, D_ = 128;
constexpr int BT_ = B_ * T_;            // 256
constexpr int VW_ = N_ * N_;            // 576
constexpr int BTN_ = BT_ * N_;          // 6144
constexpr int BTVW_ = BT_ * VW_;        // 147456
constexpr int P_ = 3;
constexpr int C_ = 6;
constexpr int SA_ = 136;                // padded A-tile row stride (u16); /2=68 u32

__device__ __forceinline__ float bits2f(u32 u) { float f; __builtin_memcpy(&f, &u, 4); return f; }
__device__ __forceinline__ float bf2f(u16 h) { return bits2f(((u32)h) << 16); }
__device__ __forceinline__ u16 f2bf(float f) {
    u32 u; __builtin_memcpy(&u, &f, 4);
    u32 r = u + 0x7FFFu + ((u >> 16) & 1u);
    return (u16)(r >> 16);
}
__device__ __forceinline__ float sigm(float x) { return 1.0f / (1.0f + expf(-x)); }

// ---------------------------------------------------------------------------
// Canonicalize all 17 weight/bias arrays (fp32 -> bf16) + build transposed
// LSTM Whh (WT[kk*1024 + j*2 + p] = Whh[j*128 + kk*2 + p]) in ONE launch.
// ---------------------------------------------------------------------------
struct CvtArgs {
    const void* src[17];
    u16* dst[17];
    int start[18];
    const float* whh;   // raw fp32 lstm_Whh  (d_in[14]!)
    u16* wthh;          // transposed bf16 out
};

__global__ __launch_bounds__(256) void k_convall(CvtArgs a) {
    const int idx = blockIdx.x * 256 + threadIdx.x;
    const int total = a.start[17];
    if (idx < total) {
        int s = 0;
#pragma unroll
        for (int i = 1; i < 17; ++i) s += (idx >= a.start[i]) ? 1 : 0;
        const int off = idx - a.start[s];
        a.dst[s][off] = f2bf(((const float*)a.src[s])[off]);
    } else {
        const int off = idx - total;
        if (off < 65536) {
            const int kk = off >> 10, rem = off & 1023;
            const int j = rem >> 1, p = rem & 1;
            a.wthh[off] = f2bf(a.whh[j * 128 + kk * 2 + p]);
        }
    }
}

// ---------------------------------------------------------------------------
// Transpose node_resnet [bt, d, n] fp32 -> HN fp32 + HNb bf16 [bt, n, d].
// ---------------------------------------------------------------------------
__global__ __launch_bounds__(256) void k_transpose_node(const float* __restrict__ node,
                                                        float* __restrict__ HN,
                                                        u16* __restrict__ HNb) {
    const int bt = blockIdx.x;
    for (int f = threadIdx.x; f < 3072; f += 256) {
        const int d = f / 24, n = f - d * 24;
        const float v = node[(size_t)bt * 3072 + f];
        HN[(size_t)bt * 3072 + n * 128 + d] = v;
        HNb[(size_t)bt * 3072 + n * 128 + d] = f2bf(v);
    }
}

// ---------------------------------------------------------------------------
// Edge transpose: edge [bt, d, vw] fp32 -> EB [bt*576+vw][d] bf16.
// ---------------------------------------------------------------------------
__global__ __launch_bounds__(256) void k_eb(const float* __restrict__ edge,
                                            u16* __restrict__ EB) {
    __shared__ float t[32][33];
    const int bt = blockIdx.x / 72;
    const int tile = blockIdx.x % 72;
    const int d0 = (tile / 18) * 32, vw0 = (tile % 18) * 32;
    const int tx = threadIdx.x & 31, ty = threadIdx.x >> 5;
    const size_t sbase = (size_t)bt * D_ * VW_;
#pragma unroll
    for (int r = 0; r < 4; ++r) {
        const int dr = ty * 4 + r;
        t[dr][tx] = edge[sbase + (size_t)(d0 + dr) * VW_ + vw0 + tx];
    }
    __syncthreads();
#pragma unroll
    for (int r = 0; r < 4; ++r) {
        const int vr = ty * 4 + r;
        EB[((size_t)bt * VW_ + vw0 + vr) * 128 + d0 + tx] = f2bf(t[tx][vr]);
    }
}

// ---------------------------------------------------------------------------
// ME = EB @ We^T via MFMA. 64 rows/block (4 waves x 16). Output bf16.
// ---------------------------------------------------------------------------
__global__ __launch_bounds__(256) void k_me(const u16* __restrict__ EB,
                                            const u16* __restrict__ We,
                                            u16* __restrict__ ME) {
    const int tid = threadIdx.x;
    const int wv = tid >> 6, lane = tid & 63;
    const int m = lane & 15, quad = lane >> 4;
    const int r0 = blockIdx.x * 64 + wv * 16;
    bf16x8 a[4];
#pragma unroll
    for (int ks = 0; ks < 4; ++ks)
        a[ks] = *(const bf16x8*)&EB[(size_t)(r0 + m) * 128 + ks * 32 + quad * 8];
    const f32x4 z = {0.f, 0.f, 0.f, 0.f};
#pragma unroll
    for (int ct = 0; ct < 8; ++ct) {
        f32x4 acc = z;
        const int n = ct * 16 + m;
#pragma unroll
        for (int ks = 0; ks < 4; ++ks) {
            const bf16x8 b = *(const bf16x8*)&We[n * 128 + ks * 32 + quad * 8];
            acc = __builtin_amdgcn_mfma_f32_16x16x32_bf16(a[ks], b, acc, 0, 0, 0);
        }
#pragma unroll
        for (int reg = 0; reg < 4; ++reg)
            ME[(size_t)(r0 + quad * 4 + reg) * 128 + ct * 16 + m] = f2bf(acc[reg]);
    }
}

// ---------------------------------------------------------------------------
// Fused per-(bt, v-pair) edge kernel. 48 rows (2 v) per block, 256 threads.
//  MSG:  build h_edge rows (gate*relu(XW+ME+mb); 0 invalid) -> A bf16 (if
//        ADJP) + MV (bf16 packed) accumulated fp32.
//  !MSG: A = raw EB rows (layer-0).
//  ADJP: link-MLP via MFMA on A -> ADJ in place (3 waves x 16 rows).
// ---------------------------------------------------------------------------
template <bool MSG, bool ADJP>
__global__ __launch_bounds__(256) void k_fused(
    const u16* __restrict__ EB, const u16* __restrict__ ME,
    const float* __restrict__ XW, const u16* __restrict__ mb,
    const u16* __restrict__ W1, const u16* __restrict__ b1,
    const u16* __restrict__ W2, const u16* __restrict__ b2,
    const int* __restrict__ nnr, float* __restrict__ ADJ,
    u16* __restrict__ MVb) {
    __shared__ __align__(16) u16 A[48 * SA_];
    __shared__ float gate_s[48];
    __shared__ float2 mvp[2][2][64];
    const int tid = threadIdx.x;
    const int blk = blockIdx.x;
    const int bt = blk / 12, pr = blk - bt * 12;
    const int v0 = pr * 2;
    const int e0 = bt * VW_ + v0 * N_;
    const int nv = nnr[bt];

    if constexpr (MSG) {
        if (tid < 48) gate_s[tid] = sigm(ADJ[e0 + tid]);
        __syncthreads();
        const int op = tid & 63;            // o-pair: cols 2op, 2op+1
        const int sub = (tid >> 6) & 1;     // w-half
        const int grp = tid >> 7;           // v within pair
        const int v = v0 + grp;
        const u32 mbu = ((const u32*)mb)[op];
        const float mb0 = bf2f((u16)mbu), mb1 = bf2f((u16)(mbu >> 16));
        float mvx = 0.0f, mvy = 0.0f;
        const bool vva = v < nv;
        u32* A32 = (u32*)A;
#pragma unroll
        for (int i = 0; i < 12; ++i) {
            const int w = sub * 12 + i;
            const int rr = grp * 24 + w;
            float v0f = 0.0f, v1f = 0.0f;
            if (vva && w < nv) {
                const u32 meu = ((const u32*)ME)[(size_t)(e0 + rr) * 64 + op];
                const float2 xwv = *(const float2*)&XW[(size_t)(bt * N_ + w) * 128 + 2 * op];
                const float g = gate_s[rr];
                v0f = g * fmaxf(xwv.x + bf2f((u16)meu) + mb0, 0.0f);
                v1f = g * fmaxf(xwv.y + bf2f((u16)(meu >> 16)) + mb1, 0.0f);
                mvx += v0f; mvy += v1f;
            }
            if (ADJP) A32[rr * 68 + op] = (u32)f2bf(v0f) | ((u32)f2bf(v1f) << 16);
        }
        mvp[grp][sub][op] = make_float2(mvx, mvy);
        __syncthreads();
        if (tid < 128) {
            const int g2 = tid >> 6, o2 = tid & 63;
            const float2 pa = mvp[g2][0][o2], pb = mvp[g2][1][o2];
            const float sx = pa.x + pb.x, sy = pa.y + pb.y;
            ((u32*)MVb)[(size_t)(bt * N_ + v0 + g2) * 64 + o2] =
                (u32)f2bf(sx) | ((u32)f2bf(sy) << 16);
        }
    } else {
        for (int f = tid; f < 768; f += 256) {
            const int rr = f >> 4, ch = f & 15;
            *(bf16x8*)&A[rr * SA_ + ch * 8] = *(const bf16x8*)&EB[(size_t)(e0 + rr) * 128 + ch * 8];
        }
        __syncthreads();
    }

    if constexpr (ADJP) {
        if (MSG) __syncthreads();   // A fully written (non-MSG already synced)
        if (tid >= 192) return;
        const int wv = tid >> 6, lane = tid & 63;
        const int m = lane & 15, quad = lane >> 4;
        bf16x8 a[4];
#pragma unroll
        for (int ks = 0; ks < 4; ++ks)
            a[ks] = *(const bf16x8*)&A[(wv * 16 + m) * SA_ + ks * 32 + quad * 8];
        f32x4 acc[8];
        const f32x4 z = {0.f, 0.f, 0.f, 0.f};
#pragma unroll
        for (int ct = 0; ct < 8; ++ct) acc[ct] = z;
#pragma unroll
        for (int ct = 0; ct < 8; ++ct) {
            const int n = ct * 16 + m;
#pragma unroll
            for (int ks = 0; ks < 4; ++ks) {
                const bf16x8 b = *(const bf16x8*)&W1[n * 128 + ks * 32 + quad * 8];
                acc[ct] = __builtin_amdgcn_mfma_f32_16x16x32_bf16(a[ks], b, acc[ct], 0, 0, 0);
            }
        }
        const float b2v = bf2f(b2[0]);
        float p[4] = {0.f, 0.f, 0.f, 0.f};
#pragma unroll
        for (int ct = 0; ct < 8; ++ct) {
            const int n = ct * 16 + m;
            const float b1v = bf2f(b1[n]);
            const float w2v = bf2f(W2[n]);
#pragma unroll
            for (int reg = 0; reg < 4; ++reg)
                p[reg] += fmaxf(acc[ct][reg] + b1v, 0.0f) * w2v;
        }
#pragma unroll
        for (int reg = 0; reg < 4; ++reg) {
            p[reg] += __shfl_xor(p[reg], 1);
            p[reg] += __shfl_xor(p[reg], 2);
            p[reg] += __shfl_xor(p[reg], 4);
            p[reg] += __shfl_xor(p[reg], 8);
        }
        if (m == 0) {
#pragma unroll
            for (int reg = 0; reg < 4; ++reg)
                ADJ[e0 + wv * 16 + quad * 4 + reg] = p[reg] + b2v;
        }
    }
}

// ---------------------------------------------------------------------------
// XW = HNb @ msg_Wh^T via MFMA. 192 blocks x 128 threads (2 waves x 16 rows).
// ---------------------------------------------------------------------------
__global__ __launch_bounds__(128) void k_xw(const u16* __restrict__ HNb,
                                            const u16* __restrict__ W,
                                            float* __restrict__ XW) {
    const int tid = threadIdx.x;
    const int wv = tid >> 6, lane = tid & 63;
    const int m = lane & 15, quad = lane >> 4;
    const int r0 = blockIdx.x * 32 + wv * 16;
    bf16x8 a[4];
#pragma unroll
    for (int ks = 0; ks < 4; ++ks)
        a[ks] = *(const bf16x8*)&HNb[(size_t)(r0 + m) * 128 + ks * 32 + quad * 8];
    const f32x4 z = {0.f, 0.f, 0.f, 0.f};
#pragma unroll
    for (int ct = 0; ct < 8; ++ct) {
        f32x4 acc = z;
        const int n = ct * 16 + m;
#pragma unroll
        for (int ks = 0; ks < 4; ++ks) {
            const bf16x8 b = *(const bf16x8*)&W[n * 128 + ks * 32 + quad * 8];
            acc = __builtin_amdgcn_mfma_f32_16x16x32_bf16(a[ks], b, acc, 0, 0, 0);
        }
#pragma unroll
        for (int reg = 0; reg < 4; ++reg)
            XW[(size_t)(r0 + quad * 4 + reg) * 128 + ct * 16 + m] = acc[reg];
    }
}

// ---------------------------------------------------------------------------
// Fused MFMA GRU: 64 rows/block (4 waves x 16), 256 threads.
// gi = MVb @ Wih^T, gh = HNb @ Whh^T (per gate), combine, masked h-update.
// Writes HN fp32 + HNb bf16 in place (wave-exclusive rows).
// ---------------------------------------------------------------------------
__global__ __launch_bounds__(256) void k_gruM(
    const u16* __restrict__ MVb, const u16* __restrict__ HNb_in,
    float* __restrict__ HN, u16* __restrict__ HNb,
    const u16* __restrict__ Wih, const u16* __restrict__ Whh,
    const u16* __restrict__ bih, const u16* __restrict__ bhh,
    const int* __restrict__ nnr) {
    __shared__ float bi_s[384], bh_s[384];
    const int tid = threadIdx.x;
    for (int f = tid; f < 384; f += 256) {
        bi_s[f] = bf2f(bih[f]);
        bh_s[f] = bf2f(bhh[f]);
    }
    const int wv = tid >> 6, lane = tid & 63;
    const int m = lane & 15, quad = lane >> 4;
    const int rbase = blockIdx.x * 64 + wv * 16;
    bf16x8 amv[4], ahn[4];
#pragma unroll
    for (int ks = 0; ks < 4; ++ks) {
        amv[ks] = *(const bf16x8*)&MVb[(size_t)(rbase + m) * 128 + ks * 32 + quad * 8];
        ahn[ks] = *(const bf16x8*)&HNb_in[(size_t)(rbase + m) * 128 + ks * 32 + quad * 8];
    }
    int rowg[4]; bool valid[4];
#pragma unroll
    for (int reg = 0; reg < 4; ++reg) {
        const int row = rbase + quad * 4 + reg;
        rowg[reg] = row;
        const int bt = row / N_, vv = row - bt * N_;
        valid[reg] = vv < nnr[bt];
    }
    __syncthreads();
    const f32x4 z = {0.f, 0.f, 0.f, 0.f};
#pragma unroll
    for (int ct = 0; ct < 8; ++ct) {
        f32x4 gi[3], gh[3];
#pragma unroll
        for (int g = 0; g < 3; ++g) { gi[g] = z; gh[g] = z; }
        const int col = ct * 16 + m;
#pragma unroll
        for (int g = 0; g < 3; ++g) {
            const size_t wrow = (size_t)(g * 128 + col) * 128;
#pragma unroll
            for (int ks = 0; ks < 4; ++ks) {
                const bf16x8 bi_f = *(const bf16x8*)&Wih[wrow + ks * 32 + quad * 8];
                const bf16x8 bh_f = *(const bf16x8*)&Whh[wrow + ks * 32 + quad * 8];
                gi[g] = __builtin_amdgcn_mfma_f32_16x16x32_bf16(amv[ks], bi_f, gi[g], 0, 0, 0);
                gh[g] = __builtin_amdgcn_mfma_f32_16x16x32_bf16(ahn[ks], bh_f, gh[g], 0, 0, 0);
            }
        }
        const float biR = bi_s[col], bhR = bh_s[col];
        const float biZ = bi_s[128 + col], bhZ = bh_s[128 + col];
        const float biN = bi_s[256 + col], bhN = bh_s[256 + col];
#pragma unroll
        for (int reg = 0; reg < 4; ++reg) {
            const float r = sigm(gi[0][reg] + gh[0][reg] + biR + bhR);
            const float zz = sigm(gi[1][reg] + gh[1][reg] + biZ + bhZ);
            const float nn = tanhf(gi[2][reg] + biN + r * (gh[2][reg] + bhN));
            const size_t oi = (size_t)rowg[reg] * 128 + col;
            const float h = HN[oi];
            const float hv = valid[reg] ? ((1.0f - zz) * nn + zz * h) : 0.0f;
            HN[oi] = hv;
            HNb[oi] = f2bf(hv);
        }
    }
}

// ---------------------------------------------------------------------------
// GI = HNb @ lstm_Wih^T + (bih+bhh). grid (192, 2) x 128 threads.
// ---------------------------------------------------------------------------
__global__ __launch_bounds__(128) void k_gi(const u16* __restrict__ HNb,
                                            const u16* __restrict__ W,
                                            const u16* __restrict__ bih, const u16* __restrict__ bhh,
                                            float* __restrict__ GI) {
    const int tid = threadIdx.x;
    const int wv = tid >> 6, lane = tid & 63;
    const int m = lane & 15, quad = lane >> 4;
    const int r0 = blockIdx.x * 32 + wv * 16;
    const int ocol0 = blockIdx.y * 256;
    bf16x8 a[4];
#pragma unroll
    for (int ks = 0; ks < 4; ++ks)
        a[ks] = *(const bf16x8*)&HNb[(size_t)(r0 + m) * 128 + ks * 32 + quad * 8];
    const f32x4 z = {0.f, 0.f, 0.f, 0.f};
#pragma unroll
    for (int ct = 0; ct < 16; ++ct) {
        f32x4 acc = z;
        const int col = ocol0 + ct * 16 + m;
#pragma unroll
        for (int ks = 0; ks < 4; ++ks) {
            const bf16x8 b = *(const bf16x8*)&W[(size_t)col * 128 + ks * 32 + quad * 8];
            acc = __builtin_amdgcn_mfma_f32_16x16x32_bf16(a[ks], b, acc, 0, 0, 0);
        }
        const float bsum = bf2f(bih[col]) + bf2f(bhh[col]);
#pragma unroll
        for (int reg = 0; reg < 4; ++reg)
            GI[(size_t)(r0 + quad * 4 + reg) * 512 + col] = acc[reg] + bsum;
    }
}

// ---------------------------------------------------------------------------
// Recurrent LSTM, Whh in registers. 192 blocks x 512 threads (1 gate out
// each); 4 independent accumulators; float4 h broadcast; GI prefetch.
// ---------------------------------------------------------------------------
__global__ __launch_bounds__(512) void k_rec(const float* __restrict__ GI,
                                             const u16* __restrict__ WThh,
                                             float* __restrict__ OUTH) {
    __shared__ __align__(16) float h_s[128];
    __shared__ __align__(16) float g_s[512];
    const int tid = threadIdx.x;
    const int row = blockIdx.x;          // b*24+n
    const int bb = row / N_, nn = row - bb * N_;
    const u32* WT32 = (const u32*)WThh;  // WT32[kk*512 + j] = (Whh[j,2kk], Whh[j,2kk+1])
    u32 wt[64];
#pragma unroll
    for (int kk = 0; kk < 64; ++kk) wt[kk] = WT32[kk * 512 + tid];
    float c = 0.0f;
    if (tid < 128) h_s[tid] = 0.0f;
    __syncthreads();
    const size_t gb = (size_t)(bb * T_ * N_ + nn) * 512;
    float g = GI[gb + tid];
    for (int t = 0; t < T_; ++t) {
        float gnext = 0.0f;
        if (t + 1 < T_) gnext = GI[gb + (size_t)(t + 1) * (N_ * 512) + tid];
        float acc[4] = {0.f, 0.f, 0.f, 0.f};
#pragma unroll
        for (int k4 = 0; k4 < 32; ++k4) {
            const float4 h4 = *(const float4*)&h_s[k4 * 4];
            const u32 wA = wt[2 * k4], wB = wt[2 * k4 + 1];
            acc[k4 & 3] = fmaf(bits2f(wA << 16), h4.x,
                          fmaf(bits2f(wA & 0xFFFF0000u), h4.y,
                          fmaf(bits2f(wB << 16), h4.z,
                          fmaf(bits2f(wB & 0xFFFF0000u), h4.w, acc[k4 & 3]))));
        }
        g_s[tid] = g + (acc[0] + acc[1]) + (acc[2] + acc[3]);
        __syncthreads();
        if (tid < 128) {
            const float gi = g_s[tid], gf = g_s[128 + tid];
            const float gg = g_s[256 + tid], go = g_s[384 + tid];
            c = sigm(gf) * c + sigm(gi) * tanhf(gg);
            const float hv = sigm(go) * tanhf(c);
            h_s[tid] = hv;
            OUTH[((size_t)t * 192 + row) * 128 + tid] = hv;
        }
        __syncthreads();
        g = gnext;
    }
}

// ---------------------------------------------------------------------------
// Readout: out[b,t,n,c] = mask ? OUTH_row . ro_W[c] + ro_b[c] : 0   (fp32 out)
// ---------------------------------------------------------------------------
__global__ __launch_bounds__(256) void k_readout(const float* __restrict__ OUTH,
                                                 const u16* __restrict__ roW,
                                                 const u16* __restrict__ rob,
                                                 const int* __restrict__ nnr,
                                                 float* __restrict__ out) {
    const int idx = blockIdx.x * 256 + threadIdx.x;
    const int btn = idx / C_, c = idx - btn * C_;
    const int bt = btn / N_, n = btn - bt * N_;
    const int b = bt / T_, t = bt - b * T_;
    const int nv = nnr[bt];
    float val = 0.0f;
    if (n < nv) {
        const float* hrow = OUTH + ((size_t)t * 192 + b * N_ + n) * 128;
        float acc = bf2f(rob[c]);
        for (int k = 0; k < 128; ++k) acc += bf2f(roW[c * 128 + k]) * hrow[k];
        val = acc;
    }
    out[idx] = val;
}

// ---------------------------------------------------------------------------
extern "C" void kernel_launch(void* const* d_in, const int* in_sizes, int n_in,
                              void* d_out, int out_size, void* d_ws, size_t ws_size,
                              hipStream_t stream) {
    const float* node = (const float*)d_in[0];
    const float* edge = (const float*)d_in[1];
    const int* nnr = (const int*)d_in[19];

    // Workspace layout (~100 MB)
    char* ws = (char*)d_ws;
    float* HN = (float*)ws;   ws += (size_t)BTN_ * D_ * 4;    // 3.15 MB
    u16* HNb = (u16*)ws;      ws += (size_t)BTN_ * D_ * 2;    // 1.57 MB
    float* XW = (float*)ws;   ws += (size_t)BTN_ * D_ * 4;    // 3.15 MB
    u16* MVb = (u16*)ws;      ws += (size_t)BTN_ * D_ * 2;    // 1.57 MB
    float* ADJ = (float*)ws;  ws += (size_t)BTVW_ * 4;        // 0.59 MB
    float* GI = (float*)ws;   ws += (size_t)BTN_ * 512 * 4;   // 12.58 MB
    u16* WThh = (u16*)ws;     ws += 65536 * 2;                // 0.13 MB
    u16* EB = (u16*)ws;       ws += (size_t)BTVW_ * D_ * 2;   // 37.75 MB
    u16* ME = (u16*)ws;       ws += (size_t)BTVW_ * D_ * 2;   // 37.75 MB
    float* OUTH = XW;         // XW dead after last k_fused; same size

    // Canonical bf16 weights
    u16* cbase = (u16*)ws;
    const int cvtN[17] = {16384, 128, 128, 1, 16384, 16384, 128,
                          49152, 49152, 384, 384, 65536, 65536, 512, 512, 768, 6};
    CvtArgs ca;
    u16* cptr[17];
    {
        int off = 0;
        for (int i = 0; i < 17; ++i) {
            cptr[i] = cbase + off;
            ca.src[i] = d_in[2 + i];
            ca.dst[i] = cptr[i];
            off += (cvtN[i] + 7) & ~7;
        }
        int cum = 0;
        for (int i = 0; i < 17; ++i) { ca.start[i] = cum; cum += cvtN[i]; }
        ca.start[17] = cum;             // 281479
        ca.whh = (const float*)d_in[14];   // lstm_Whh (FIXED: was d_in[16]=lstm_bhh)
        ca.wthh = WThh;
    }
    u16* cW1 = cptr[0];  u16* cb1 = cptr[1];  u16* cW2 = cptr[2];  u16* cb2 = cptr[3];
    u16* cWh = cptr[4];  u16* cWe = cptr[5];  u16* cmb = cptr[6];
    u16* cgWih = cptr[7]; u16* cgWhh = cptr[8]; u16* cgbih = cptr[9]; u16* cgbhh = cptr[10];
    u16* clsWih = cptr[11]; u16* clsbih = cptr[13]; u16* clsbhh = cptr[14];
    u16* croW = cptr[15]; u16* crob = cptr[16];

    k_convall<<<(281479 + 65536 + 255) / 256, 256, 0, stream>>>(ca);
    k_transpose_node<<<BT_, 256, 0, stream>>>(node, HN, HNb);
    k_eb<<<BT_ * 72, 256, 0, stream>>>(edge, EB);
    k_me<<<BTVW_ / 64, 256, 0, stream>>>(EB, cWe, ME);
    k_fused<false, true><<<BTN_ / 2, 256, 0, stream>>>(EB, ME, XW, cmb, cW1, cb1, cW2, cb2,
                                                       nnr, ADJ, MVb);
    for (int l = 0; l < P_; ++l) {
        k_xw<<<192, 128, 0, stream>>>(HNb, cWh, XW);
        if (l < P_ - 1)
            k_fused<true, true><<<BTN_ / 2, 256, 0, stream>>>(EB, ME, XW, cmb, cW1, cb1, cW2, cb2,
                                                              nnr, ADJ, MVb);
        else
            k_fused<true, false><<<BTN_ / 2, 256, 0, stream>>>(EB, ME, XW, cmb, cW1, cb1, cW2, cb2,
                                                               nnr, ADJ, MVb);
        k_gruM<<<96, 256, 0, stream>>>(MVb, HNb, HN, HNb, cgWih, cgWhh, cgbih, cgbhh, nnr);
    }
    k_gi<<<dim3(192, 2), 128, 0, stream>>>(HNb, clsWih, clsbih, clsbhh, GI);
    k_rec<<<192, 512, 0, stream>>>(GI, WThh, OUTH);
    k_readout<<<144, 256, 0, stream>>>(OUTH, croW, crob, nnr, (float*)d_out);
}

// Round 9
// 531.421 us; speedup vs baseline: 3.2458x; 1.0182x over previous
//
#include <hip/hip_runtime.h>
#include <cmath>

typedef unsigned short u16;
typedef unsigned int   u32;
typedef short bf16x8 __attribute__((ext_vector_type(8)));
typedef float f32x4 __attribute__((ext_vector_type(4)));

// Problem constants
constexpr int B_ = 8, T_ = 32, N_ = 24, D_ = 128;
constexpr int BT_ = B_ * T_;            // 256
constexpr int VW_ = N_ * N_;            // 576
constexpr int BTN_ = BT_ * N_;          // 6144
constexpr int BTVW_ = BT_ * VW_;        // 147456
constexpr int P_ = 3;
constexpr int C_ = 6;
constexpr int SA_ = 136;                // padded A-tile row stride (u16); /2=68 u32

__device__ __forceinline__ float bits2f(u32 u) { float f; __builtin_memcpy(&f, &u, 4); return f; }
__device__ __forceinline__ float bf2f(u16 h) { return bits2f(((u32)h) << 16); }
__device__ __forceinline__ u16 f2bf(float f) {
    u32 u; __builtin_memcpy(&u, &f, 4);
    u32 r = u + 0x7FFFu + ((u >> 16) & 1u);
    return (u16)(r >> 16);
}
__device__ __forceinline__ float sigm(float x) { return 1.0f / (1.0f + expf(-x)); }

// ---------------------------------------------------------------------------
// Canonicalize all 17 weight/bias arrays (fp32 -> bf16) + build transposed
// LSTM Whh (WT[kk*1024 + j*2 + p] = Whh[j*128 + kk*2 + p]) in ONE launch.
// ---------------------------------------------------------------------------
struct CvtArgs {
    const void* src[17];
    u16* dst[17];
    int start[18];
    const float* whh;   // raw fp32 lstm_Whh (d_in[14])
    u16* wthh;          // transposed bf16 out
};

__global__ __launch_bounds__(256) void k_convall(CvtArgs a) {
    const int idx = blockIdx.x * 256 + threadIdx.x;
    const int total = a.start[17];
    if (idx < total) {
        int s = 0;
#pragma unroll
        for (int i = 1; i < 17; ++i) s += (idx >= a.start[i]) ? 1 : 0;
        const int off = idx - a.start[s];
        a.dst[s][off] = f2bf(((const float*)a.src[s])[off]);
    } else {
        const int off = idx - total;
        if (off < 65536) {
            const int kk = off >> 10, rem = off & 1023;
            const int j = rem >> 1, p = rem & 1;
            a.wthh[off] = f2bf(a.whh[j * 128 + kk * 2 + p]);
        }
    }
}

// ---------------------------------------------------------------------------
// Transpose node_resnet [bt, d, n] fp32 -> HN fp32 + HNb bf16 [bt, n, d].
// ---------------------------------------------------------------------------
__global__ __launch_bounds__(256) void k_transpose_node(const float* __restrict__ node,
                                                        float* __restrict__ HN,
                                                        u16* __restrict__ HNb) {
    const int bt = blockIdx.x;
    for (int f = threadIdx.x; f < 3072; f += 256) {
        const int d = f / 24, n = f - d * 24;
        const float v = node[(size_t)bt * 3072 + f];
        HN[(size_t)bt * 3072 + n * 128 + d] = v;
        HNb[(size_t)bt * 3072 + n * 128 + d] = f2bf(v);
    }
}

// ---------------------------------------------------------------------------
// k_prep: fused edge transpose + ME GEMM + layer-0 link-MLP.
// Per block: (bt, 64 vw-rows). Stage raw edge rows (bf16) into LDS A via
// 32x32 float tiles; then 4 waves x 16 rows MFMA: ME = A @ We^T (bf16 out)
// and adj0 = W2.relu(W1 @ A + b1) + b2. EB buffer eliminated entirely.
// ---------------------------------------------------------------------------
__global__ __launch_bounds__(256) void k_prep(
    const float* __restrict__ edge, const u16* __restrict__ We,
    const u16* __restrict__ W1, const u16* __restrict__ b1,
    const u16* __restrict__ W2, const u16* __restrict__ b2,
    u16* __restrict__ ME, float* __restrict__ ADJ) {
    __shared__ __align__(16) u16 A[64 * SA_];
    __shared__ __align__(16) float t[32][33];
    const int tid = threadIdx.x;
    const int bt = blockIdx.x / 9, tile = blockIdx.x % 9;
    const int vw0 = tile * 64;
    const int tx = tid & 31, ty = tid >> 5;   // ty 0..7
    const size_t ebase = (size_t)bt * D_ * VW_;
    for (int dt = 0; dt < 4; ++dt) {
        for (int vt = 0; vt < 2; ++vt) {
            __syncthreads();
#pragma unroll
            for (int r = 0; r < 4; ++r) {
                const int d = dt * 32 + ty * 4 + r;
                t[ty * 4 + r][tx] = edge[ebase + (size_t)d * VW_ + vw0 + vt * 32 + tx];
            }
            __syncthreads();
#pragma unroll
            for (int r = 0; r < 4; ++r) {
                const int vr = ty * 4 + r;
                A[(vt * 32 + vr) * SA_ + dt * 32 + tx] = f2bf(t[tx][vr]);
            }
        }
    }
    __syncthreads();

    const int wv = tid >> 6, lane = tid & 63;
    const int m = lane & 15, quad = lane >> 4;
    bf16x8 a[4];
#pragma unroll
    for (int ks = 0; ks < 4; ++ks)
        a[ks] = *(const bf16x8*)&A[(wv * 16 + m) * SA_ + ks * 32 + quad * 8];
    const f32x4 z = {0.f, 0.f, 0.f, 0.f};
    // ME tile
#pragma unroll
    for (int ct = 0; ct < 8; ++ct) {
        f32x4 acc = z;
        const int n = ct * 16 + m;
#pragma unroll
        for (int ks = 0; ks < 4; ++ks) {
            const bf16x8 b = *(const bf16x8*)&We[n * 128 + ks * 32 + quad * 8];
            acc = __builtin_amdgcn_mfma_f32_16x16x32_bf16(a[ks], b, acc, 0, 0, 0);
        }
#pragma unroll
        for (int reg = 0; reg < 4; ++reg)
            ME[(size_t)(bt * VW_ + vw0 + wv * 16 + quad * 4 + reg) * 128 + n] = f2bf(acc[reg]);
    }
    // layer-0 adjacency
    f32x4 acc2[8];
#pragma unroll
    for (int ct = 0; ct < 8; ++ct) acc2[ct] = z;
#pragma unroll
    for (int ct = 0; ct < 8; ++ct) {
        const int n = ct * 16 + m;
#pragma unroll
        for (int ks = 0; ks < 4; ++ks) {
            const bf16x8 b = *(const bf16x8*)&W1[n * 128 + ks * 32 + quad * 8];
            acc2[ct] = __builtin_amdgcn_mfma_f32_16x16x32_bf16(a[ks], b, acc2[ct], 0, 0, 0);
        }
    }
    const float b2v = bf2f(b2[0]);
    float p[4] = {0.f, 0.f, 0.f, 0.f};
#pragma unroll
    for (int ct = 0; ct < 8; ++ct) {
        const int n = ct * 16 + m;
        const float b1v = bf2f(b1[n]);
        const float w2v = bf2f(W2[n]);
#pragma unroll
        for (int reg = 0; reg < 4; ++reg)
            p[reg] += fmaxf(acc2[ct][reg] + b1v, 0.0f) * w2v;
    }
#pragma unroll
    for (int reg = 0; reg < 4; ++reg) {
        p[reg] += __shfl_xor(p[reg], 1);
        p[reg] += __shfl_xor(p[reg], 2);
        p[reg] += __shfl_xor(p[reg], 4);
        p[reg] += __shfl_xor(p[reg], 8);
    }
    if (m == 0) {
#pragma unroll
        for (int reg = 0; reg < 4; ++reg)
            ADJ[bt * VW_ + vw0 + wv * 16 + quad * 4 + reg] = p[reg] + b2v;
    }
}

// ---------------------------------------------------------------------------
// Fused per-(bt, v-pair) edge kernel. 48 rows (2 v) per block, 256 threads.
// MSG build with UNCONDITIONAL batched loads (24 in flight), masked compute.
// ADJP: link-MLP via MFMA on A -> next-layer ADJ in place (3 waves).
// ---------------------------------------------------------------------------
template <bool ADJP>
__global__ __launch_bounds__(256) void k_fused(
    const u16* __restrict__ ME, const float* __restrict__ XW,
    const u16* __restrict__ mb,
    const u16* __restrict__ W1, const u16* __restrict__ b1,
    const u16* __restrict__ W2, const u16* __restrict__ b2,
    const int* __restrict__ nnr, float* __restrict__ ADJ,
    u16* __restrict__ MVb) {
    __shared__ __align__(16) u16 A[48 * SA_];
    __shared__ float gate_s[48];
    __shared__ float2 mvp[2][2][64];
    const int tid = threadIdx.x;
    const int blk = blockIdx.x;
    const int bt = blk / 12, pr = blk - bt * 12;
    const int v0 = pr * 2;
    const int e0 = bt * VW_ + v0 * N_;
    const int nv = nnr[bt];

    if (tid < 48) gate_s[tid] = sigm(ADJ[e0 + tid]);
    __syncthreads();
    {
        const int op = tid & 63;            // o-pair: cols 2op, 2op+1
        const int sub = (tid >> 6) & 1;     // w-half
        const int grp = tid >> 7;           // v within pair
        const int v = v0 + grp;
        const u32 mbu = ((const u32*)mb)[op];
        const float mb0 = bf2f((u16)mbu), mb1 = bf2f((u16)(mbu >> 16));
        const bool vva = v < nv;
        // batched unconditional loads (rows of invalid pairs are defined: 0)
        u32 meR[12]; float2 xwR[12];
#pragma unroll
        for (int i = 0; i < 12; ++i) {
            const int w = sub * 12 + i;
            const int rr = grp * 24 + w;
            meR[i] = ((const u32*)ME)[(size_t)(e0 + rr) * 64 + op];
            xwR[i] = *(const float2*)&XW[(size_t)(bt * N_ + w) * 128 + 2 * op];
        }
        float mvx = 0.0f, mvy = 0.0f;
        u32* A32 = (u32*)A;
#pragma unroll
        for (int i = 0; i < 12; ++i) {
            const int w = sub * 12 + i;
            const int rr = grp * 24 + w;
            float v0f = 0.0f, v1f = 0.0f;
            if (vva && w < nv) {
                const float g = gate_s[rr];
                v0f = g * fmaxf(xwR[i].x + bf2f((u16)meR[i]) + mb0, 0.0f);
                v1f = g * fmaxf(xwR[i].y + bf2f((u16)(meR[i] >> 16)) + mb1, 0.0f);
                mvx += v0f; mvy += v1f;
            }
            if (ADJP) A32[rr * 68 + op] = (u32)f2bf(v0f) | ((u32)f2bf(v1f) << 16);
        }
        mvp[grp][sub][op] = make_float2(mvx, mvy);
    }
    __syncthreads();
    if (tid < 128) {
        const int g2 = tid >> 6, o2 = tid & 63;
        const float2 pa = mvp[g2][0][o2], pb = mvp[g2][1][o2];
        ((u32*)MVb)[(size_t)(bt * N_ + v0 + g2) * 64 + o2] =
            (u32)f2bf(pa.x + pb.x) | ((u32)f2bf(pa.y + pb.y) << 16);
    }

    if constexpr (ADJP) {
        __syncthreads();
        if (tid >= 192) return;
        const int wv = tid >> 6, lane = tid & 63;
        const int m = lane & 15, quad = lane >> 4;
        bf16x8 a[4];
#pragma unroll
        for (int ks = 0; ks < 4; ++ks)
            a[ks] = *(const bf16x8*)&A[(wv * 16 + m) * SA_ + ks * 32 + quad * 8];
        f32x4 acc[8];
        const f32x4 z = {0.f, 0.f, 0.f, 0.f};
#pragma unroll
        for (int ct = 0; ct < 8; ++ct) acc[ct] = z;
#pragma unroll
        for (int ct = 0; ct < 8; ++ct) {
            const int n = ct * 16 + m;
#pragma unroll
            for (int ks = 0; ks < 4; ++ks) {
                const bf16x8 b = *(const bf16x8*)&W1[n * 128 + ks * 32 + quad * 8];
                acc[ct] = __builtin_amdgcn_mfma_f32_16x16x32_bf16(a[ks], b, acc[ct], 0, 0, 0);
            }
        }
        const float b2v = bf2f(b2[0]);
        float p[4] = {0.f, 0.f, 0.f, 0.f};
#pragma unroll
        for (int ct = 0; ct < 8; ++ct) {
            const int n = ct * 16 + m;
            const float b1v = bf2f(b1[n]);
            const float w2v = bf2f(W2[n]);
#pragma unroll
            for (int reg = 0; reg < 4; ++reg)
                p[reg] += fmaxf(acc[ct][reg] + b1v, 0.0f) * w2v;
        }
#pragma unroll
        for (int reg = 0; reg < 4; ++reg) {
            p[reg] += __shfl_xor(p[reg], 1);
            p[reg] += __shfl_xor(p[reg], 2);
            p[reg] += __shfl_xor(p[reg], 4);
            p[reg] += __shfl_xor(p[reg], 8);
        }
        if (m == 0) {
#pragma unroll
            for (int reg = 0; reg < 4; ++reg)
                ADJ[e0 + wv * 16 + quad * 4 + reg] = p[reg] + b2v;
        }
    }
}

// ---------------------------------------------------------------------------
// XW = HNb @ msg_Wh^T via MFMA. 192 blocks x 128 threads (2 waves x 16 rows).
// ---------------------------------------------------------------------------
__global__ __launch_bounds__(128) void k_xw(const u16* __restrict__ HNb,
                                            const u16* __restrict__ W,
                                            float* __restrict__ XW) {
    const int tid = threadIdx.x;
    const int wv = tid >> 6, lane = tid & 63;
    const int m = lane & 15, quad = lane >> 4;
    const int r0 = blockIdx.x * 32 + wv * 16;
    bf16x8 a[4];
#pragma unroll
    for (int ks = 0; ks < 4; ++ks)
        a[ks] = *(const bf16x8*)&HNb[(size_t)(r0 + m) * 128 + ks * 32 + quad * 8];
    const f32x4 z = {0.f, 0.f, 0.f, 0.f};
#pragma unroll
    for (int ct = 0; ct < 8; ++ct) {
        f32x4 acc = z;
        const int n = ct * 16 + m;
#pragma unroll
        for (int ks = 0; ks < 4; ++ks) {
            const bf16x8 b = *(const bf16x8*)&W[n * 128 + ks * 32 + quad * 8];
            acc = __builtin_amdgcn_mfma_f32_16x16x32_bf16(a[ks], b, acc, 0, 0, 0);
        }
#pragma unroll
        for (int reg = 0; reg < 4; ++reg)
            XW[(size_t)(r0 + quad * 4 + reg) * 128 + ct * 16 + m] = acc[reg];
    }
}

// ---------------------------------------------------------------------------
// Fused MFMA GRU: 32 rows/block (2 waves x 16), 128 threads, 192 blocks.
// ---------------------------------------------------------------------------
__global__ __launch_bounds__(128) void k_gruM(
    const u16* __restrict__ MVb, const u16* __restrict__ HNb_in,
    float* __restrict__ HN, u16* __restrict__ HNb,
    const u16* __restrict__ Wih, const u16* __restrict__ Whh,
    const u16* __restrict__ bih, const u16* __restrict__ bhh,
    const int* __restrict__ nnr) {
    __shared__ float bi_s[384], bh_s[384];
    const int tid = threadIdx.x;
    for (int f = tid; f < 384; f += 128) {
        bi_s[f] = bf2f(bih[f]);
        bh_s[f] = bf2f(bhh[f]);
    }
    const int wv = tid >> 6, lane = tid & 63;
    const int m = lane & 15, quad = lane >> 4;
    const int rbase = blockIdx.x * 32 + wv * 16;
    bf16x8 amv[4], ahn[4];
#pragma unroll
    for (int ks = 0; ks < 4; ++ks) {
        amv[ks] = *(const bf16x8*)&MVb[(size_t)(rbase + m) * 128 + ks * 32 + quad * 8];
        ahn[ks] = *(const bf16x8*)&HNb_in[(size_t)(rbase + m) * 128 + ks * 32 + quad * 8];
    }
    int rowg[4]; bool valid[4];
#pragma unroll
    for (int reg = 0; reg < 4; ++reg) {
        const int row = rbase + quad * 4 + reg;
        rowg[reg] = row;
        const int bt = row / N_, vv = row - bt * N_;
        valid[reg] = vv < nnr[bt];
    }
    __syncthreads();
    const f32x4 z = {0.f, 0.f, 0.f, 0.f};
#pragma unroll
    for (int ct = 0; ct < 8; ++ct) {
        f32x4 gi[3], gh[3];
#pragma unroll
        for (int g = 0; g < 3; ++g) { gi[g] = z; gh[g] = z; }
        const int col = ct * 16 + m;
#pragma unroll
        for (int g = 0; g < 3; ++g) {
            const size_t wrow = (size_t)(g * 128 + col) * 128;
#pragma unroll
            for (int ks = 0; ks < 4; ++ks) {
                const bf16x8 bi_f = *(const bf16x8*)&Wih[wrow + ks * 32 + quad * 8];
                const bf16x8 bh_f = *(const bf16x8*)&Whh[wrow + ks * 32 + quad * 8];
                gi[g] = __builtin_amdgcn_mfma_f32_16x16x32_bf16(amv[ks], bi_f, gi[g], 0, 0, 0);
                gh[g] = __builtin_amdgcn_mfma_f32_16x16x32_bf16(ahn[ks], bh_f, gh[g], 0, 0, 0);
            }
        }
        const float biR = bi_s[col], bhR = bh_s[col];
        const float biZ = bi_s[128 + col], bhZ = bh_s[128 + col];
        const float biN = bi_s[256 + col], bhN = bh_s[256 + col];
#pragma unroll
        for (int reg = 0; reg < 4; ++reg) {
            const float r = sigm(gi[0][reg] + gh[0][reg] + biR + bhR);
            const float zz = sigm(gi[1][reg] + gh[1][reg] + biZ + bhZ);
            const float nn = tanhf(gi[2][reg] + biN + r * (gh[2][reg] + bhN));
            const size_t oi = (size_t)rowg[reg] * 128 + col;
            const float h = HN[oi];
            const float hv = valid[reg] ? ((1.0f - zz) * nn + zz * h) : 0.0f;
            HN[oi] = hv;
            HNb[oi] = f2bf(hv);
        }
    }
}

// ---------------------------------------------------------------------------
// GI = HNb @ lstm_Wih^T + (bih+bhh). grid (192, 2) x 128 threads.
// ---------------------------------------------------------------------------
__global__ __launch_bounds__(128) void k_gi(const u16* __restrict__ HNb,
                                            const u16* __restrict__ W,
                                            const u16* __restrict__ bih, const u16* __restrict__ bhh,
                                            float* __restrict__ GI) {
    const int tid = threadIdx.x;
    const int wv = tid >> 6, lane = tid & 63;
    const int m = lane & 15, quad = lane >> 4;
    const int r0 = blockIdx.x * 32 + wv * 16;
    const int ocol0 = blockIdx.y * 256;
    bf16x8 a[4];
#pragma unroll
    for (int ks = 0; ks < 4; ++ks)
        a[ks] = *(const bf16x8*)&HNb[(size_t)(r0 + m) * 128 + ks * 32 + quad * 8];
    const f32x4 z = {0.f, 0.f, 0.f, 0.f};
#pragma unroll
    for (int ct = 0; ct < 16; ++ct) {
        f32x4 acc = z;
        const int col = ocol0 + ct * 16 + m;
#pragma unroll
        for (int ks = 0; ks < 4; ++ks) {
            const bf16x8 b = *(const bf16x8*)&W[(size_t)col * 128 + ks * 32 + quad * 8];
            acc = __builtin_amdgcn_mfma_f32_16x16x32_bf16(a[ks], b, acc, 0, 0, 0);
        }
        const float bsum = bf2f(bih[col]) + bf2f(bhh[col]);
#pragma unroll
        for (int reg = 0; reg < 4; ++reg)
            GI[(size_t)(r0 + quad * 4 + reg) * 512 + col] = acc[reg] + bsum;
    }
}

// ---------------------------------------------------------------------------
// Recurrent LSTM, Whh in registers. 192 blocks x 512 threads.
// ---------------------------------------------------------------------------
__global__ __launch_bounds__(512) void k_rec(const float* __restrict__ GI,
                                             const u16* __restrict__ WThh,
                                             float* __restrict__ OUTH) {
    __shared__ __align__(16) float h_s[128];
    __shared__ __align__(16) float g_s[512];
    const int tid = threadIdx.x;
    const int row = blockIdx.x;          // b*24+n
    const int bb = row / N_, nn = row - bb * N_;
    const u32* WT32 = (const u32*)WThh;
    u32 wt[64];
#pragma unroll
    for (int kk = 0; kk < 64; ++kk) wt[kk] = WT32[kk * 512 + tid];
    float c = 0.0f;
    if (tid < 128) h_s[tid] = 0.0f;
    __syncthreads();
    const size_t gb = (size_t)(bb * T_ * N_ + nn) * 512;
    float g = GI[gb + tid];
    for (int t = 0; t < T_; ++t) {
        float gnext = 0.0f;
        if (t + 1 < T_) gnext = GI[gb + (size_t)(t + 1) * (N_ * 512) + tid];
        float acc[4] = {0.f, 0.f, 0.f, 0.f};
#pragma unroll
        for (int k4 = 0; k4 < 32; ++k4) {
            const float4 h4 = *(const float4*)&h_s[k4 * 4];
            const u32 wA = wt[2 * k4], wB = wt[2 * k4 + 1];
            acc[k4 & 3] = fmaf(bits2f(wA << 16), h4.x,
                          fmaf(bits2f(wA & 0xFFFF0000u), h4.y,
                          fmaf(bits2f(wB << 16), h4.z,
                          fmaf(bits2f(wB & 0xFFFF0000u), h4.w, acc[k4 & 3]))));
        }
        g_s[tid] = g + (acc[0] + acc[1]) + (acc[2] + acc[3]);
        __syncthreads();
        if (tid < 128) {
            const float gi = g_s[tid], gf = g_s[128 + tid];
            const float gg = g_s[256 + tid], go = g_s[384 + tid];
            c = sigm(gf) * c + sigm(gi) * tanhf(gg);
            const float hv = sigm(go) * tanhf(c);
            h_s[tid] = hv;
            OUTH[((size_t)t * 192 + row) * 128 + tid] = hv;
        }
        __syncthreads();
        g = gnext;
    }
}

// ---------------------------------------------------------------------------
// Readout: out[b,t,n,c] = mask ? OUTH_row . ro_W[c] + ro_b[c] : 0   (fp32 out)
// ---------------------------------------------------------------------------
__global__ __launch_bounds__(256) void k_readout(const float* __restrict__ OUTH,
                                                 const u16* __restrict__ roW,
                                                 const u16* __restrict__ rob,
                                                 const int* __restrict__ nnr,
                                                 float* __restrict__ out) {
    const int idx = blockIdx.x * 256 + threadIdx.x;
    const int btn = idx / C_, c = idx - btn * C_;
    const int bt = btn / N_, n = btn - bt * N_;
    const int b = bt / T_, t = bt - b * T_;
    const int nv = nnr[bt];
    float val = 0.0f;
    if (n < nv) {
        const float* hrow = OUTH + ((size_t)t * 192 + b * N_ + n) * 128;
        float acc = bf2f(rob[c]);
        for (int k = 0; k < 128; ++k) acc += bf2f(roW[c * 128 + k]) * hrow[k];
        val = acc;
    }
    out[idx] = val;
}

// ---------------------------------------------------------------------------
extern "C" void kernel_launch(void* const* d_in, const int* in_sizes, int n_in,
                              void* d_out, int out_size, void* d_ws, size_t ws_size,
                              hipStream_t stream) {
    const float* node = (const float*)d_in[0];
    const float* edge = (const float*)d_in[1];
    const int* nnr = (const int*)d_in[19];

    // Workspace layout (~62 MB; EB eliminated)
    char* ws = (char*)d_ws;
    float* HN = (float*)ws;   ws += (size_t)BTN_ * D_ * 4;    // 3.15 MB
    u16* HNb = (u16*)ws;      ws += (size_t)BTN_ * D_ * 2;    // 1.57 MB
    float* XW = (float*)ws;   ws += (size_t)BTN_ * D_ * 4;    // 3.15 MB
    u16* MVb = (u16*)ws;      ws += (size_t)BTN_ * D_ * 2;    // 1.57 MB
    float* ADJ = (float*)ws;  ws += (size_t)BTVW_ * 4;        // 0.59 MB
    float* GI = (float*)ws;   ws += (size_t)BTN_ * 512 * 4;   // 12.58 MB
    u16* WThh = (u16*)ws;     ws += 65536 * 2;                // 0.13 MB
    u16* ME = (u16*)ws;       ws += (size_t)BTVW_ * D_ * 2;   // 37.75 MB
    float* OUTH = XW;         // XW dead after last k_fused; same size

    // Canonical bf16 weights
    u16* cbase = (u16*)ws;
    const int cvtN[17] = {16384, 128, 128, 1, 16384, 16384, 128,
                          49152, 49152, 384, 384, 65536, 65536, 512, 512, 768, 6};
    CvtArgs ca;
    u16* cptr[17];
    {
        int off = 0;
        for (int i = 0; i < 17; ++i) {
            cptr[i] = cbase + off;
            ca.src[i] = d_in[2 + i];
            ca.dst[i] = cptr[i];
            off += (cvtN[i] + 7) & ~7;
        }
        int cum = 0;
        for (int i = 0; i < 17; ++i) { ca.start[i] = cum; cum += cvtN[i]; }
        ca.start[17] = cum;             // 281479
        ca.whh = (const float*)d_in[14];   // lstm_Whh
        ca.wthh = WThh;
    }
    u16* cW1 = cptr[0];  u16* cb1 = cptr[1];  u16* cW2 = cptr[2];  u16* cb2 = cptr[3];
    u16* cWh = cptr[4];  u16* cWe = cptr[5];  u16* cmb = cptr[6];
    u16* cgWih = cptr[7]; u16* cgWhh = cptr[8]; u16* cgbih = cptr[9]; u16* cgbhh = cptr[10];
    u16* clsWih = cptr[11]; u16* clsbih = cptr[13]; u16* clsbhh = cptr[14];
    u16* croW = cptr[15]; u16* crob = cptr[16];

    k_convall<<<(281479 + 65536 + 255) / 256, 256, 0, stream>>>(ca);
    k_transpose_node<<<BT_, 256, 0, stream>>>(node, HN, HNb);
    // fused: edge transpose + ME GEMM + layer-0 adjacency
    k_prep<<<BT_ * 9, 256, 0, stream>>>(edge, cWe, cW1, cb1, cW2, cb2, ME, ADJ);
    for (int l = 0; l < P_; ++l) {
        k_xw<<<192, 128, 0, stream>>>(HNb, cWh, XW);
        if (l < P_ - 1)
            k_fused<true><<<BTN_ / 2, 256, 0, stream>>>(ME, XW, cmb, cW1, cb1, cW2, cb2,
                                                        nnr, ADJ, MVb);
        else
            k_fused<false><<<BTN_ / 2, 256, 0, stream>>>(ME, XW, cmb, cW1, cb1, cW2, cb2,
                                                         nnr, ADJ, MVb);
        k_gruM<<<192, 128, 0, stream>>>(MVb, HNb, HN, HNb, cgWih, cgWhh, cgbih, cgbhh, nnr);
    }
    k_gi<<<dim3(192, 2), 128, 0, stream>>>(HNb, clsWih, clsbih, clsbhh, GI);
    k_rec<<<192, 512, 0, stream>>>(GI, WThh, OUTH);
    k_readout<<<144, 256, 0, stream>>>(OUTH, croW, crob, nnr, (float*)d_out);
}

// Round 10
// 485.537 us; speedup vs baseline: 3.5526x; 1.0945x over previous
//
#include <hip/hip_runtime.h>
#include <cmath>

typedef unsigned short u16;
typedef unsigned int   u32;
typedef short bf16x8 __attribute__((ext_vector_type(8)));
typedef float f32x4 __attribute__((ext_vector_type(4)));

// Problem constants
constexpr int B_ = 8, T_ = 32, N_ = 24, D_ = 128;
constexpr int BT_ = B_ * T_;            // 256
constexpr int VW_ = N_ * N_;            // 576
constexpr int BTN_ = BT_ * N_;          // 6144
constexpr int BTVW_ = BT_ * VW_;        // 147456
constexpr int P_ = 3;
constexpr int C_ = 6;
constexpr int SA_ = 136;                // k_fused A row stride (u16); /2=68 u32

__device__ __forceinline__ float bits2f(u32 u) { float f; __builtin_memcpy(&f, &u, 4); return f; }
__device__ __forceinline__ float bf2f(u16 h) { return bits2f(((u32)h) << 16); }
__device__ __forceinline__ u16 f2bf(float f) {
    u32 u; __builtin_memcpy(&u, &f, 4);
    u32 r = u + 0x7FFFu + ((u >> 16) & 1u);
    return (u16)(r >> 16);
}
__device__ __forceinline__ float sigm(float x) { return 1.0f / (1.0f + expf(-x)); }

// ---------------------------------------------------------------------------
// Canonicalize all 17 weight/bias arrays (fp32 -> bf16) + build transposed
// LSTM Whh (WT[kk*1024 + j*2 + p] = Whh[j*128 + kk*2 + p]) in ONE launch.
// ---------------------------------------------------------------------------
struct CvtArgs {
    const void* src[17];
    u16* dst[17];
    int start[18];
    const float* whh;   // raw fp32 lstm_Whh (d_in[14])
    u16* wthh;          // transposed bf16 out
};

__global__ __launch_bounds__(256) void k_convall(CvtArgs a) {
    const int idx = blockIdx.x * 256 + threadIdx.x;
    const int total = a.start[17];
    if (idx < total) {
        int s = 0;
#pragma unroll
        for (int i = 1; i < 17; ++i) s += (idx >= a.start[i]) ? 1 : 0;
        const int off = idx - a.start[s];
        a.dst[s][off] = f2bf(((const float*)a.src[s])[off]);
    } else {
        const int off = idx - total;
        if (off < 65536) {
            const int kk = off >> 10, rem = off & 1023;
            const int j = rem >> 1, p = rem & 1;
            a.wthh[off] = f2bf(a.whh[j * 128 + kk * 2 + p]);
        }
    }
}

// ---------------------------------------------------------------------------
// Transpose node_resnet [bt, d, n] fp32 -> HN fp32 + HNb bf16 [bt, n, d].
// ---------------------------------------------------------------------------
__global__ __launch_bounds__(256) void k_transpose_node(const float* __restrict__ node,
                                                        float* __restrict__ HN,
                                                        u16* __restrict__ HNb) {
    const int bt = blockIdx.x;
    for (int f = threadIdx.x; f < 3072; f += 256) {
        const int d = f / 24, n = f - d * 24;
        const float v = node[(size_t)bt * 3072 + f];
        HN[(size_t)bt * 3072 + n * 128 + d] = v;
        HNb[(size_t)bt * 3072 + n * 128 + d] = f2bf(v);
    }
}

// ---------------------------------------------------------------------------
// k_prep: fused edge transpose + ME GEMM + layer-0 link-MLP.
// Per block: (bt, 64 vw rows). Single-barrier staging: 8 independent float4
// loads/thread -> bf16-pair u32 writes into XOR-swizzled A
// (A16[row*128 + (col ^ ((row>>2&7)*8))]) -- 2-way banks on write (free).
// MFMA with B-fragments preloaded to registers in 4-ct halves.
// ---------------------------------------------------------------------------
__global__ __launch_bounds__(256) void k_prep(
    const float* __restrict__ edge, const u16* __restrict__ We,
    const u16* __restrict__ W1, const u16* __restrict__ b1,
    const u16* __restrict__ W2, const u16* __restrict__ b2,
    u16* __restrict__ ME, float* __restrict__ ADJ) {
    __shared__ __align__(16) u16 A[64 * 128];   // swizzled, 16 KB
    const int tid = threadIdx.x;
    const int bt = blockIdx.x / 9, tile = blockIdx.x % 9;
    const int vw0 = tile * 64;
    const size_t ebase = (size_t)bt * D_ * VW_ + vw0;
    // ---- staging: all loads up front, one barrier ----
    const int vq = tid & 15, dg = tid >> 4;     // vq: vw-quad, dg: d-pair group
    float4 fa[4], fb[4];
#pragma unroll
    for (int it = 0; it < 4; ++it) {
        const int d0 = it * 32 + dg * 2;
        fa[it] = *(const float4*)&edge[ebase + (size_t)d0 * VW_ + vq * 4];
        fb[it] = *(const float4*)&edge[ebase + (size_t)(d0 + 1) * VW_ + vq * 4];
    }
    u32* A32 = (u32*)A;
#pragma unroll
    for (int it = 0; it < 4; ++it) {
        const int d0 = it * 32 + dg * 2;
        const float* pa = (const float*)&fa[it];
        const float* pb = (const float*)&fb[it];
#pragma unroll
        for (int i = 0; i < 4; ++i) {
            const int row = vq * 4 + i;
            const int sw32 = ((row >> 2) & 7) * 4;   // u32-unit swizzle
            A32[row * 64 + ((d0 >> 1) ^ sw32)] =
                (u32)f2bf(pa[i]) | ((u32)f2bf(pb[i]) << 16);
        }
    }
    __syncthreads();
    // ---- fragments ----
    const int wv = tid >> 6, lane = tid & 63;
    const int m = lane & 15, quad = lane >> 4;
    const int row = wv * 16 + m;
    const int sw16 = ((row >> 2) & 7) * 8;
    bf16x8 a[4];
#pragma unroll
    for (int ks = 0; ks < 4; ++ks)
        a[ks] = *(const bf16x8*)&A[row * 128 + ((ks * 32 + quad * 8) ^ sw16)];
    const f32x4 z = {0.f, 0.f, 0.f, 0.f};
    // ---- ME = A @ We^T, register-B halves ----
#pragma unroll
    for (int h = 0; h < 2; ++h) {
        bf16x8 bw[4][4];
#pragma unroll
        for (int c4 = 0; c4 < 4; ++c4)
#pragma unroll
            for (int ks = 0; ks < 4; ++ks)
                bw[c4][ks] = *(const bf16x8*)&We[(size_t)((h * 4 + c4) * 16 + m) * 128 + ks * 32 + quad * 8];
        f32x4 acc[4];
#pragma unroll
        for (int c4 = 0; c4 < 4; ++c4) acc[c4] = z;
#pragma unroll
        for (int c4 = 0; c4 < 4; ++c4)
#pragma unroll
            for (int ks = 0; ks < 4; ++ks)
                acc[c4] = __builtin_amdgcn_mfma_f32_16x16x32_bf16(a[ks], bw[c4][ks], acc[c4], 0, 0, 0);
#pragma unroll
        for (int c4 = 0; c4 < 4; ++c4)
#pragma unroll
            for (int reg = 0; reg < 4; ++reg)
                ME[(size_t)(bt * VW_ + vw0 + wv * 16 + quad * 4 + reg) * 128 +
                   (h * 4 + c4) * 16 + m] = f2bf(acc[c4][reg]);
    }
    // ---- layer-0 adjacency: relu(W1@A + b1) . W2 + b2 ----
    float p[4] = {0.f, 0.f, 0.f, 0.f};
    const float b2v = bf2f(b2[0]);
#pragma unroll
    for (int h = 0; h < 2; ++h) {
        bf16x8 bw[4][4];
#pragma unroll
        for (int c4 = 0; c4 < 4; ++c4)
#pragma unroll
            for (int ks = 0; ks < 4; ++ks)
                bw[c4][ks] = *(const bf16x8*)&W1[(size_t)((h * 4 + c4) * 16 + m) * 128 + ks * 32 + quad * 8];
        f32x4 acc[4];
#pragma unroll
        for (int c4 = 0; c4 < 4; ++c4) acc[c4] = z;
#pragma unroll
        for (int c4 = 0; c4 < 4; ++c4)
#pragma unroll
            for (int ks = 0; ks < 4; ++ks)
                acc[c4] = __builtin_amdgcn_mfma_f32_16x16x32_bf16(a[ks], bw[c4][ks], acc[c4], 0, 0, 0);
#pragma unroll
        for (int c4 = 0; c4 < 4; ++c4) {
            const int n = (h * 4 + c4) * 16 + m;
            const float b1v = bf2f(b1[n]);
            const float w2v = bf2f(W2[n]);
#pragma unroll
            for (int reg = 0; reg < 4; ++reg)
                p[reg] += fmaxf(acc[c4][reg] + b1v, 0.0f) * w2v;
        }
    }
#pragma unroll
    for (int reg = 0; reg < 4; ++reg) {
        p[reg] += __shfl_xor(p[reg], 1);
        p[reg] += __shfl_xor(p[reg], 2);
        p[reg] += __shfl_xor(p[reg], 4);
        p[reg] += __shfl_xor(p[reg], 8);
    }
    if (m == 0) {
#pragma unroll
        for (int reg = 0; reg < 4; ++reg)
            ADJ[bt * VW_ + vw0 + wv * 16 + quad * 4 + reg] = p[reg] + b2v;
    }
}

// ---------------------------------------------------------------------------
// Fused per-(bt, v-pair) edge kernel. 48 rows (2 v) per block, 256 threads.
// Build phase: batched unconditional loads, masked compute. ADJP: link-MLP
// via MFMA with register-preloaded W1 fragments (3 waves x 16 rows).
// ---------------------------------------------------------------------------
template <bool ADJP>
__global__ __launch_bounds__(256) void k_fused(
    const u16* __restrict__ ME, const float* __restrict__ XW,
    const u16* __restrict__ mb,
    const u16* __restrict__ W1, const u16* __restrict__ b1,
    const u16* __restrict__ W2, const u16* __restrict__ b2,
    const int* __restrict__ nnr, float* __restrict__ ADJ,
    u16* __restrict__ MVb) {
    __shared__ __align__(16) u16 A[48 * SA_];
    __shared__ float gate_s[48];
    __shared__ float2 mvp[2][2][64];
    const int tid = threadIdx.x;
    const int blk = blockIdx.x;
    const int bt = blk / 12, pr = blk - bt * 12;
    const int v0 = pr * 2;
    const int e0 = bt * VW_ + v0 * N_;
    const int nv = nnr[bt];

    if (tid < 48) gate_s[tid] = sigm(ADJ[e0 + tid]);
    __syncthreads();
    {
        const int op = tid & 63;            // o-pair: cols 2op, 2op+1
        const int sub = (tid >> 6) & 1;     // w-half
        const int grp = tid >> 7;           // v within pair
        const int v = v0 + grp;
        const u32 mbu = ((const u32*)mb)[op];
        const float mb0 = bf2f((u16)mbu), mb1 = bf2f((u16)(mbu >> 16));
        const bool vva = v < nv;
        u32 meR[12]; float2 xwR[12];
#pragma unroll
        for (int i = 0; i < 12; ++i) {
            const int w = sub * 12 + i;
            const int rr = grp * 24 + w;
            meR[i] = ((const u32*)ME)[(size_t)(e0 + rr) * 64 + op];
            xwR[i] = *(const float2*)&XW[(size_t)(bt * N_ + w) * 128 + 2 * op];
        }
        float mvx = 0.0f, mvy = 0.0f;
        u32* A32 = (u32*)A;
#pragma unroll
        for (int i = 0; i < 12; ++i) {
            const int w = sub * 12 + i;
            const int rr = grp * 24 + w;
            float v0f = 0.0f, v1f = 0.0f;
            if (vva && w < nv) {
                const float g = gate_s[rr];
                v0f = g * fmaxf(xwR[i].x + bf2f((u16)meR[i]) + mb0, 0.0f);
                v1f = g * fmaxf(xwR[i].y + bf2f((u16)(meR[i] >> 16)) + mb1, 0.0f);
                mvx += v0f; mvy += v1f;
            }
            if (ADJP) A32[rr * 68 + op] = (u32)f2bf(v0f) | ((u32)f2bf(v1f) << 16);
        }
        mvp[grp][sub][op] = make_float2(mvx, mvy);
    }
    __syncthreads();
    if (tid < 128) {
        const int g2 = tid >> 6, o2 = tid & 63;
        const float2 pa = mvp[g2][0][o2], pb = mvp[g2][1][o2];
        ((u32*)MVb)[(size_t)(bt * N_ + v0 + g2) * 64 + o2] =
            (u32)f2bf(pa.x + pb.x) | ((u32)f2bf(pa.y + pb.y) << 16);
    }

    if constexpr (ADJP) {
        __syncthreads();
        if (tid >= 192) return;
        const int wv = tid >> 6, lane = tid & 63;
        const int m = lane & 15, quad = lane >> 4;
        bf16x8 a[4];
#pragma unroll
        for (int ks = 0; ks < 4; ++ks)
            a[ks] = *(const bf16x8*)&A[(wv * 16 + m) * SA_ + ks * 32 + quad * 8];
        const f32x4 z = {0.f, 0.f, 0.f, 0.f};
        float p[4] = {0.f, 0.f, 0.f, 0.f};
        const float b2v = bf2f(b2[0]);
#pragma unroll
        for (int h = 0; h < 2; ++h) {
            bf16x8 bw[4][4];
#pragma unroll
            for (int c4 = 0; c4 < 4; ++c4)
#pragma unroll
                for (int ks = 0; ks < 4; ++ks)
                    bw[c4][ks] = *(const bf16x8*)&W1[(size_t)((h * 4 + c4) * 16 + m) * 128 + ks * 32 + quad * 8];
            f32x4 acc[4];
#pragma unroll
            for (int c4 = 0; c4 < 4; ++c4) acc[c4] = z;
#pragma unroll
            for (int c4 = 0; c4 < 4; ++c4)
#pragma unroll
                for (int ks = 0; ks < 4; ++ks)
                    acc[c4] = __builtin_amdgcn_mfma_f32_16x16x32_bf16(a[ks], bw[c4][ks], acc[c4], 0, 0, 0);
#pragma unroll
            for (int c4 = 0; c4 < 4; ++c4) {
                const int n = (h * 4 + c4) * 16 + m;
                const float b1v = bf2f(b1[n]);
                const float w2v = bf2f(W2[n]);
#pragma unroll
                for (int reg = 0; reg < 4; ++reg)
                    p[reg] += fmaxf(acc[c4][reg] + b1v, 0.0f) * w2v;
            }
        }
#pragma unroll
        for (int reg = 0; reg < 4; ++reg) {
            p[reg] += __shfl_xor(p[reg], 1);
            p[reg] += __shfl_xor(p[reg], 2);
            p[reg] += __shfl_xor(p[reg], 4);
            p[reg] += __shfl_xor(p[reg], 8);
        }
        if (m == 0) {
#pragma unroll
            for (int reg = 0; reg < 4; ++reg)
                ADJ[e0 + wv * 16 + quad * 4 + reg] = p[reg] + b2v;
        }
    }
}

// ---------------------------------------------------------------------------
// XW = HNb @ msg_Wh^T via MFMA. 192 blocks x 128 threads (2 waves x 16 rows).
// ---------------------------------------------------------------------------
__global__ __launch_bounds__(128) void k_xw(const u16* __restrict__ HNb,
                                            const u16* __restrict__ W,
                                            float* __restrict__ XW) {
    const int tid = threadIdx.x;
    const int wv = tid >> 6, lane = tid & 63;
    const int m = lane & 15, quad = lane >> 4;
    const int r0 = blockIdx.x * 32 + wv * 16;
    bf16x8 a[4];
#pragma unroll
    for (int ks = 0; ks < 4; ++ks)
        a[ks] = *(const bf16x8*)&HNb[(size_t)(r0 + m) * 128 + ks * 32 + quad * 8];
    const f32x4 z = {0.f, 0.f, 0.f, 0.f};
#pragma unroll
    for (int ct = 0; ct < 8; ++ct) {
        f32x4 acc = z;
        const int n = ct * 16 + m;
#pragma unroll
        for (int ks = 0; ks < 4; ++ks) {
            const bf16x8 b = *(const bf16x8*)&W[n * 128 + ks * 32 + quad * 8];
            acc = __builtin_amdgcn_mfma_f32_16x16x32_bf16(a[ks], b, acc, 0, 0, 0);
        }
#pragma unroll
        for (int reg = 0; reg < 4; ++reg)
            XW[(size_t)(r0 + quad * 4 + reg) * 128 + ct * 16 + m] = acc[reg];
    }
}

// ---------------------------------------------------------------------------
// Fused MFMA GRU: 32 rows/block (2 waves x 16), 128 threads, 192 blocks.
// ---------------------------------------------------------------------------
__global__ __launch_bounds__(128) void k_gruM(
    const u16* __restrict__ MVb, const u16* __restrict__ HNb_in,
    float* __restrict__ HN, u16* __restrict__ HNb,
    const u16* __restrict__ Wih, const u16* __restrict__ Whh,
    const u16* __restrict__ bih, const u16* __restrict__ bhh,
    const int* __restrict__ nnr) {
    __shared__ float bi_s[384], bh_s[384];
    const int tid = threadIdx.x;
    for (int f = tid; f < 384; f += 128) {
        bi_s[f] = bf2f(bih[f]);
        bh_s[f] = bf2f(bhh[f]);
    }
    const int wv = tid >> 6, lane = tid & 63;
    const int m = lane & 15, quad = lane >> 4;
    const int rbase = blockIdx.x * 32 + wv * 16;
    bf16x8 amv[4], ahn[4];
#pragma unroll
    for (int ks = 0; ks < 4; ++ks) {
        amv[ks] = *(const bf16x8*)&MVb[(size_t)(rbase + m) * 128 + ks * 32 + quad * 8];
        ahn[ks] = *(const bf16x8*)&HNb_in[(size_t)(rbase + m) * 128 + ks * 32 + quad * 8];
    }
    int rowg[4]; bool valid[4];
#pragma unroll
    for (int reg = 0; reg < 4; ++reg) {
        const int row = rbase + quad * 4 + reg;
        rowg[reg] = row;
        const int bt = row / N_, vv = row - bt * N_;
        valid[reg] = vv < nnr[bt];
    }
    __syncthreads();
    const f32x4 z = {0.f, 0.f, 0.f, 0.f};
#pragma unroll
    for (int ct = 0; ct < 8; ++ct) {
        f32x4 gi[3], gh[3];
#pragma unroll
        for (int g = 0; g < 3; ++g) { gi[g] = z; gh[g] = z; }
        const int col = ct * 16 + m;
#pragma unroll
        for (int g = 0; g < 3; ++g) {
            const size_t wrow = (size_t)(g * 128 + col) * 128;
#pragma unroll
            for (int ks = 0; ks < 4; ++ks) {
                const bf16x8 bi_f = *(const bf16x8*)&Wih[wrow + ks * 32 + quad * 8];
                const bf16x8 bh_f = *(const bf16x8*)&Whh[wrow + ks * 32 + quad * 8];
                gi[g] = __builtin_amdgcn_mfma_f32_16x16x32_bf16(amv[ks], bi_f, gi[g], 0, 0, 0);
                gh[g] = __builtin_amdgcn_mfma_f32_16x16x32_bf16(ahn[ks], bh_f, gh[g], 0, 0, 0);
            }
        }
        const float biR = bi_s[col], bhR = bh_s[col];
        const float biZ = bi_s[128 + col], bhZ = bh_s[128 + col];
        const float biN = bi_s[256 + col], bhN = bh_s[256 + col];
#pragma unroll
        for (int reg = 0; reg < 4; ++reg) {
            const float r = sigm(gi[0][reg] + gh[0][reg] + biR + bhR);
            const float zz = sigm(gi[1][reg] + gh[1][reg] + biZ + bhZ);
            const float nn = tanhf(gi[2][reg] + biN + r * (gh[2][reg] + bhN));
            const size_t oi = (size_t)rowg[reg] * 128 + col;
            const float h = HN[oi];
            const float hv = valid[reg] ? ((1.0f - zz) * nn + zz * h) : 0.0f;
            HN[oi] = hv;
            HNb[oi] = f2bf(hv);
        }
    }
}

// ---------------------------------------------------------------------------
// GI = HNb @ lstm_Wih^T + (bih+bhh). grid (192, 2) x 128 threads.
// ---------------------------------------------------------------------------
__global__ __launch_bounds__(128) void k_gi(const u16* __restrict__ HNb,
                                            const u16* __restrict__ W,
                                            const u16* __restrict__ bih, const u16* __restrict__ bhh,
                                            float* __restrict__ GI) {
    const int tid = threadIdx.x;
    const int wv = tid >> 6, lane = tid & 63;
    const int m = lane & 15, quad = lane >> 4;
    const int r0 = blockIdx.x * 32 + wv * 16;
    const int ocol0 = blockIdx.y * 256;
    bf16x8 a[4];
#pragma unroll
    for (int ks = 0; ks < 4; ++ks)
        a[ks] = *(const bf16x8*)&HNb[(size_t)(r0 + m) * 128 + ks * 32 + quad * 8];
    const f32x4 z = {0.f, 0.f, 0.f, 0.f};
#pragma unroll
    for (int ct = 0; ct < 16; ++ct) {
        f32x4 acc = z;
        const int col = ocol0 + ct * 16 + m;
#pragma unroll
        for (int ks = 0; ks < 4; ++ks) {
            const bf16x8 b = *(const bf16x8*)&W[(size_t)col * 128 + ks * 32 + quad * 8];
            acc = __builtin_amdgcn_mfma_f32_16x16x32_bf16(a[ks], b, acc, 0, 0, 0);
        }
        const float bsum = bf2f(bih[col]) + bf2f(bhh[col]);
#pragma unroll
        for (int reg = 0; reg < 4; ++reg)
            GI[(size_t)(r0 + quad * 4 + reg) * 512 + col] = acc[reg] + bsum;
    }
}

// ---------------------------------------------------------------------------
// Recurrent LSTM, Whh in registers. 192 blocks x 512 threads.
// ---------------------------------------------------------------------------
__global__ __launch_bounds__(512) void k_rec(const float* __restrict__ GI,
                                             const u16* __restrict__ WThh,
                                             float* __restrict__ OUTH) {
    __shared__ __align__(16) float h_s[128];
    __shared__ __align__(16) float g_s[512];
    const int tid = threadIdx.x;
    const int row = blockIdx.x;          // b*24+n
    const int bb = row / N_, nn = row - bb * N_;
    const u32* WT32 = (const u32*)WThh;
    u32 wt[64];
#pragma unroll
    for (int kk = 0; kk < 64; ++kk) wt[kk] = WT32[kk * 512 + tid];
    float c = 0.0f;
    if (tid < 128) h_s[tid] = 0.0f;
    __syncthreads();
    const size_t gb = (size_t)(bb * T_ * N_ + nn) * 512;
    float g = GI[gb + tid];
    for (int t = 0; t < T_; ++t) {
        float gnext = 0.0f;
        if (t + 1 < T_) gnext = GI[gb + (size_t)(t + 1) * (N_ * 512) + tid];
        float acc[4] = {0.f, 0.f, 0.f, 0.f};
#pragma unroll
        for (int k4 = 0; k4 < 32; ++k4) {
            const float4 h4 = *(const float4*)&h_s[k4 * 4];
            const u32 wA = wt[2 * k4], wB = wt[2 * k4 + 1];
            acc[k4 & 3] = fmaf(bits2f(wA << 16), h4.x,
                          fmaf(bits2f(wA & 0xFFFF0000u), h4.y,
                          fmaf(bits2f(wB << 16), h4.z,
                          fmaf(bits2f(wB & 0xFFFF0000u), h4.w, acc[k4 & 3]))));
        }
        g_s[tid] = g + (acc[0] + acc[1]) + (acc[2] + acc[3]);
        __syncthreads();
        if (tid < 128) {
            const float gi = g_s[tid], gf = g_s[128 + tid];
            const float gg = g_s[256 + tid], go = g_s[384 + tid];
            c = sigm(gf) * c + sigm(gi) * tanhf(gg);
            const float hv = sigm(go) * tanhf(c);
            h_s[tid] = hv;
            OUTH[((size_t)t * 192 + row) * 128 + tid] = hv;
        }
        __syncthreads();
        g = gnext;
    }
}

// ---------------------------------------------------------------------------
// Readout: out[b,t,n,c] = mask ? OUTH_row . ro_W[c] + ro_b[c] : 0   (fp32 out)
// ---------------------------------------------------------------------------
__global__ __launch_bounds__(256) void k_readout(const float* __restrict__ OUTH,
                                                 const u16* __restrict__ roW,
                                                 const u16* __restrict__ rob,
                                                 const int* __restrict__ nnr,
                                                 float* __restrict__ out) {
    const int idx = blockIdx.x * 256 + threadIdx.x;
    const int btn = idx / C_, c = idx - btn * C_;
    const int bt = btn / N_, n = btn - bt * N_;
    const int b = bt / T_, t = bt - b * T_;
    const int nv = nnr[bt];
    float val = 0.0f;
    if (n < nv) {
        const float* hrow = OUTH + ((size_t)t * 192 + b * N_ + n) * 128;
        float acc = bf2f(rob[c]);
        for (int k = 0; k < 128; ++k) acc += bf2f(roW[c * 128 + k]) * hrow[k];
        val = acc;
    }
    out[idx] = val;
}

// ---------------------------------------------------------------------------
extern "C" void kernel_launch(void* const* d_in, const int* in_sizes, int n_in,
                              void* d_out, int out_size, void* d_ws, size_t ws_size,
                              hipStream_t stream) {
    const float* node = (const float*)d_in[0];
    const float* edge = (const float*)d_in[1];
    const int* nnr = (const int*)d_in[19];

    // Workspace layout (~62 MB)
    char* ws = (char*)d_ws;
    float* HN = (float*)ws;   ws += (size_t)BTN_ * D_ * 4;    // 3.15 MB
    u16* HNb = (u16*)ws;      ws += (size_t)BTN_ * D_ * 2;    // 1.57 MB
    float* XW = (float*)ws;   ws += (size_t)BTN_ * D_ * 4;    // 3.15 MB
    u16* MVb = (u16*)ws;      ws += (size_t)BTN_ * D_ * 2;    // 1.57 MB
    float* ADJ = (float*)ws;  ws += (size_t)BTVW_ * 4;        // 0.59 MB
    float* GI = (float*)ws;   ws += (size_t)BTN_ * 512 * 4;   // 12.58 MB
    u16* WThh = (u16*)ws;     ws += 65536 * 2;                // 0.13 MB
    u16* ME = (u16*)ws;       ws += (size_t)BTVW_ * D_ * 2;   // 37.75 MB
    float* OUTH = XW;         // XW dead after last k_fused; same size

    // Canonical bf16 weights
    u16* cbase = (u16*)ws;
    const int cvtN[17] = {16384, 128, 128, 1, 16384, 16384, 128,
                          49152, 49152, 384, 384, 65536, 65536, 512, 512, 768, 6};
    CvtArgs ca;
    u16* cptr[17];
    {
        int off = 0;
        for (int i = 0; i < 17; ++i) {
            cptr[i] = cbase + off;
            ca.src[i] = d_in[2 + i];
            ca.dst[i] = cptr[i];
            off += (cvtN[i] + 7) & ~7;
        }
        int cum = 0;
        for (int i = 0; i < 17; ++i) { ca.start[i] = cum; cum += cvtN[i]; }
        ca.start[17] = cum;             // 281479
        ca.whh = (const float*)d_in[14];   // lstm_Whh
        ca.wthh = WThh;
    }
    u16* cW1 = cptr[0];  u16* cb1 = cptr[1];  u16* cW2 = cptr[2];  u16* cb2 = cptr[3];
    u16* cWh = cptr[4];  u16* cWe = cptr[5];  u16* cmb = cptr[6];
    u16* cgWih = cptr[7]; u16* cgWhh = cptr[8]; u16* cgbih = cptr[9]; u16* cgbhh = cptr[10];
    u16* clsWih = cptr[11]; u16* clsbih = cptr[13]; u16* clsbhh = cptr[14];
    u16* croW = cptr[15]; u16* crob = cptr[16];

    k_convall<<<(281479 + 65536 + 255) / 256, 256, 0, stream>>>(ca);
    k_transpose_node<<<BT_, 256, 0, stream>>>(node, HN, HNb);
    // fused: edge transpose + ME GEMM + layer-0 adjacency (single-barrier)
    k_prep<<<BT_ * 9, 256, 0, stream>>>(edge, cWe, cW1, cb1, cW2, cb2, ME, ADJ);
    for (int l = 0; l < P_; ++l) {
        k_xw<<<192, 128, 0, stream>>>(HNb, cWh, XW);
        if (l < P_ - 1)
            k_fused<true><<<BTN_ / 2, 256, 0, stream>>>(ME, XW, cmb, cW1, cb1, cW2, cb2,
                                                        nnr, ADJ, MVb);
        else
            k_fused<false><<<BTN_ / 2, 256, 0, stream>>>(ME, XW, cmb, cW1, cb1, cW2, cb2,
                                                         nnr, ADJ, MVb);
        k_gruM<<<192, 128, 0, stream>>>(MVb, HNb, HN, HNb, cgWih, cgWhh, cgbih, cgbhh, nnr);
    }
    k_gi<<<dim3(192, 2), 128, 0, stream>>>(HNb, clsWih, clsbih, clsbhh, GI);
    k_rec<<<192, 512, 0, stream>>>(GI, WThh, OUTH);
    k_readout<<<144, 256, 0, stream>>>(OUTH, croW, crob, nnr, (float*)d_out);
}